// Round 7
// baseline (64323.645 us; speedup 1.0000x reference)
//
#include <hip/hip_runtime.h>
#include <math.h>

#define NBATCH 8
#define NATOM  256
#define NP1    257
#define WROW   258
#define TOTALK 9261
#define KC     16

#define TWO_PI_D 6.283185307179586
#define DIAG_SUB 0.7978845608028654   /* 2/sqrt(2*pi) */

// ---------------- shared-memory layouts ----------------
struct BuildSh {
  double US[2][3][64];
  double kn1[KC], kn2[KC], kn3[KC], kg[KC];
  double cI[KC][64], sI[KC][64], cJ[KC][64], sJ[KC][64];
  double ivs[9];
  double prefs;
};
struct SolveSh {
  double prow[WROW];
  double ft[NP1];
  double xs[NP1];
  double red[256];
  int    perm[NP1];
};

// ---------------- tile builder: A[ti:ti+64, tj:tj+64] for batch b ----------------
__device__ void build_tile(int b, int ti, int tj, int tid,
                           const float* __restrict__ pos,
                           const float* __restrict__ cell,
                           double* __restrict__ A, BuildSh& S)
{
  const int tx = tid & 15, ty = tid >> 4;
  const int ro = ty << 2, co = tx << 2;

  if (tid == 0) {
    double c[9];
#pragma unroll
    for (int i = 0; i < 9; i++) c[i] = (double)cell[b*9+i];
    double det = c[0]*(c[4]*c[8]-c[5]*c[7]) - c[1]*(c[3]*c[8]-c[5]*c[6])
               + c[2]*(c[3]*c[7]-c[4]*c[6]);
    double idet = 1.0/det;
    S.ivs[0]=(c[4]*c[8]-c[5]*c[7])*idet; S.ivs[1]=(c[2]*c[7]-c[1]*c[8])*idet; S.ivs[2]=(c[1]*c[5]-c[2]*c[4])*idet;
    S.ivs[3]=(c[5]*c[6]-c[3]*c[8])*idet; S.ivs[4]=(c[0]*c[8]-c[2]*c[6])*idet; S.ivs[5]=(c[2]*c[3]-c[0]*c[5])*idet;
    S.ivs[6]=(c[3]*c[7]-c[4]*c[6])*idet; S.ivs[7]=(c[1]*c[6]-c[0]*c[7])*idet; S.ivs[8]=(c[0]*c[4]-c[1]*c[3])*idet;
    S.prefs = 2.0*TWO_PI_D/fabs(det);      // 4*pi / V
  }
  __syncthreads();
  if (tid < 128) {
    int side = tid >> 6;
    int a = tid & 63;
    int atom = (side == 0) ? (ti + a) : (tj + a);
    double x = (double)pos[((size_t)b*NATOM+atom)*3+0];
    double y = (double)pos[((size_t)b*NATOM+atom)*3+1];
    double z = (double)pos[((size_t)b*NATOM+atom)*3+2];
    S.US[side][0][a] = TWO_PI_D*(S.ivs[0]*x + S.ivs[3]*y + S.ivs[6]*z);
    S.US[side][1][a] = TWO_PI_D*(S.ivs[1]*x + S.ivs[4]*y + S.ivs[7]*z);
    S.US[side][2][a] = TWO_PI_D*(S.ivs[2]*x + S.ivs[5]*y + S.ivs[8]*z);
  }
  double acc[16];
#pragma unroll
  for (int i = 0; i < 16; i++) acc[i] = 0.0;
  const double ksqmax = (TWO_PI_D/1.5)*(TWO_PI_D/1.5);
  __syncthreads();

  for (int m0 = 0; m0 < TOTALK; m0 += KC) {
    if (tid < KC) {
      int m = m0 + tid;
      double g = 0.0, d1 = 0.0, d2 = 0.0, d3 = 0.0;
      if (m < TOTALK) {
        int n1 = m/441 - 10;
        int n2 = (m/21)%21 - 10;
        int n3 = m%21 - 10;
        d1 = (double)n1; d2 = (double)n2; d3 = (double)n3;
        double kx = TWO_PI_D*(S.ivs[0]*d1 + S.ivs[1]*d2 + S.ivs[2]*d3);
        double ky = TWO_PI_D*(S.ivs[3]*d1 + S.ivs[4]*d2 + S.ivs[5]*d3);
        double kz = TWO_PI_D*(S.ivs[6]*d1 + S.ivs[7]*d2 + S.ivs[8]*d3);
        double k2 = kx*kx + ky*ky + kz*kz;
        if (k2 > 1e-10 && k2 < ksqmax) g = S.prefs*exp(-0.5*k2)/k2;
      }
      S.kn1[tid] = d1; S.kn2[tid] = d2; S.kn3[tid] = d3; S.kg[tid] = g;
    }
    __syncthreads();
#pragma unroll
    for (int p = 0; p < 8; p++) {
      int idx = p*256 + tid;
      int i    = idx & 63;
      int kk   = (idx >> 6) & (KC-1);
      int side = idx >> 10;
      double phi = S.kn1[kk]*S.US[side][0][i] + S.kn2[kk]*S.US[side][1][i]
                 + S.kn3[kk]*S.US[side][2][i];
      double sn = sin(phi);
      double cs = cos(phi);
      if (side == 0) { double g = S.kg[kk]; S.cI[kk][i] = g*cs; S.sI[kk][i] = g*sn; }
      else           { S.cJ[kk][i] = cs;    S.sJ[kk][i] = sn; }
    }
    __syncthreads();
#pragma unroll
    for (int kk = 0; kk < KC; kk++) {
      double ci[4], si[4], cj[4], sj[4];
#pragma unroll
      for (int r = 0; r < 4; r++) {
        ci[r] = S.cI[kk][ro+r]; si[r] = S.sI[kk][ro+r];
        cj[r] = S.cJ[kk][co+r]; sj[r] = S.sJ[kk][co+r];
      }
#pragma unroll
      for (int r = 0; r < 4; r++)
#pragma unroll
        for (int cc = 0; cc < 4; cc++)
          acc[r*4+cc] += ci[r]*cj[cc] + si[r]*sj[cc];
    }
    __syncthreads();
  }
#pragma unroll
  for (int r = 0; r < 4; r++) {
    int gr = ti + ro + r;
#pragma unroll
    for (int cc = 0; cc < 4; cc++) {
      int gc = tj + co + cc;
      A[((size_t)b*NATOM + gr)*NATOM + gc] = acc[r*4+cc];
    }
  }
  __syncthreads();
}

// ---------------- K1 (x16 launches): one tile per block, grid 8 = batches ----------------
__global__ __launch_bounds__(256) void build_A_k(
    const float* __restrict__ pos, const float* __restrict__ cell,
    double* __restrict__ A, int tile)
{
  __shared__ BuildSh S;
  build_tile(blockIdx.x, (tile >> 2)*64, (tile & 3)*64, threadIdx.x, pos, cell, A, S);
}

// ---------------- K2: monolithic solve (grid 8): heal + aug + GE + outputs ----------------
__global__ __launch_bounds__(256) void solve_all(
    double* __restrict__ A, double* __restrict__ aug,
    const float* __restrict__ pos, const float* __restrict__ cell,
    const void* __restrict__ c0, const void* __restrict__ c1, const void* __restrict__ c2,
    const float* __restrict__ Jraw, const float* __restrict__ syschg,
    float* __restrict__ out)
{
  const int b = blockIdx.x;
  const int tid = threadIdx.x;
  const int lane = tid & 63;
  double* Ab = A + (size_t)b*NATOM*NATOM;
  double* Pb = aug + (size_t)b*NP1*WROW;

  __shared__ union ShU { BuildSh bs; SolveSh ss; } sh;
  __shared__ int pivsh;

  // ---- classify chi / znum among the three 2048-elem candidates ----
  const float* chi = nullptr;
  const int*   znum = nullptr;
  {
    const void* cands[3] = {c0, c1, c2};
    int got = 0;
    for (int i = 0; i < 3; i++) {
      unsigned u = ((const unsigned*)cands[i])[0];
      if (u == 0u) continue;                                         // batch
      else if (u < 16u) { znum = (const int*)cands[i]; got |= 1; }   // z in {1,6,7,8}
      else              { chi  = (const float*)cands[i]; got |= 2; } // float bits
    }
    if (got != 3) { chi = (const float*)c0; znum = (const int*)c1; }
  }

  // ---- heal: rebuild A_b in-kernel if zero/poison/NaN/absurd ----
  {
    double s = 0.0;
    for (int p = tid; p < NATOM*NATOM; p += 256) s += fabs(Ab[p]);
    sh.ss.red[tid] = s;
    __syncthreads();
    for (int st = 128; st > 0; st >>= 1) {
      if (tid < st) sh.ss.red[tid] += sh.ss.red[tid + st];
      __syncthreads();
    }
    double sum = sh.ss.red[0];
    __syncthreads();
    if (!(sum > 1e-8 && sum < 1e12)) {
      for (int t = 0; t < 16; t++)
        build_tile(b, (t >> 2)*64, (t & 3)*64, tid, pos, cell, Ab - (size_t)b*NATOM*NATOM, sh.bs);
      __syncthreads();
    }
  }

  // ---- build augmented system [A+diag(J^2)-sub  1 | -chi ; 1  0 | rhsN] ----
  const double rhsN = (double)syschg[b] * sqrt(90.0474);   // Q / NORM_FACTOR
  const float J0 = Jraw[0], J1 = Jraw[1], J2 = Jraw[2], J3 = Jraw[3];
  for (int p = tid; p < NP1*WROW; p += 256) {
    int r  = p / WROW;
    int jc = p - r*WROW;
    double v;
    if (r < NATOM) {
      if (jc < NATOM) {
        v = Ab[(size_t)r*NATOM + jc];
        if (jc == r) {
          int z = znum[b*NATOM + r];
          float Jr = (z == 1) ? J0 : (z == 6) ? J1 : (z == 7) ? J2 : J3;
          v += (double)Jr*(double)Jr - DIAG_SUB;
        }
      } else if (jc == NATOM) v = 1.0;
      else                    v = -(double)chi[b*NATOM + r];
    } else {
      v = (jc < NATOM) ? 1.0 : ((jc == NATOM) ? 0.0 : rhsN);
    }
    Pb[p] = v;
  }
  __syncthreads();

  // ---- unblocked Gaussian elimination with partial pivoting (row indirection) ----
  for (int i = tid; i < NP1; i += 256) sh.ss.perm[i] = i;
  __syncthreads();

  for (int k = 0; k < NP1; k++) {
    // pivot search over positions i in [k, NP1)
    if (tid < 64) {
      double best = -1.0; int bi = k;
      for (int i = k + lane; i < NP1; i += 64) {
        double av = fabs(Pb[(size_t)sh.ss.perm[i]*WROW + k]);
        if (av > best) { best = av; bi = i; }
      }
#pragma unroll
      for (int off = 32; off > 0; off >>= 1) {
        double ov = __shfl_down(best, off);
        int    oi = __shfl_down(bi, off);
        if (ov > best) { best = ov; bi = oi; }
      }
      if (lane == 0) pivsh = bi;
    }
    __syncthreads();
    if (tid == 0) {
      int pv = pivsh;
      int t = sh.ss.perm[k]; sh.ss.perm[k] = sh.ss.perm[pv]; sh.ss.perm[pv] = t;
    }
    __syncthreads();
    const size_t rowk = (size_t)sh.ss.perm[k]*WROW;
    // cache pivot row in LDS
    for (int j = k + tid; j < WROW; j += 256) sh.ss.prow[j] = Pb[rowk + j];
    __syncthreads();
    const double dinv = 1.0 / sh.ss.prow[k];
    // factors
    for (int i = k + 1 + tid; i < NP1; i += 256)
      sh.ss.ft[i] = Pb[(size_t)sh.ss.perm[i]*WROW + k] * dinv;
    __syncthreads();
    // eliminate
    for (int i = k + 1 + tid; i < NP1; i += 256) {
      const double f = sh.ss.ft[i];
      const size_t row = (size_t)sh.ss.perm[i]*WROW;
      for (int j = k + 1; j < WROW; j++)
        Pb[row + j] -= f * sh.ss.prow[j];
    }
    __syncthreads();
  }

  // ---- backsolve (U in permuted rows; rhs eliminated along) ----
  for (int r = tid; r < NP1; r += 256)
    sh.ss.xs[r] = Pb[(size_t)sh.ss.perm[r]*WROW + 257];
  __syncthreads();
  for (int i = NP1 - 1; i >= 0; i--) {
    if (tid == 0) sh.ss.xs[i] /= Pb[(size_t)sh.ss.perm[i]*WROW + i];
    __syncthreads();
    double xi = sh.ss.xs[i];
    for (int r = tid; r < i; r += 256)
      sh.ss.xs[r] -= Pb[(size_t)sh.ss.perm[r]*WROW + i] * xi;
    __syncthreads();
  }

  // ---- outputs ----
  for (int i = tid; i < NATOM; i += 256) out[b*NATOM + i] = (float)sh.ss.xs[i];
  const double lam = sh.ss.xs[NATOM];
  // e = -0.5 * ( q.chi + lam*(Q/NF) + sum J^2 q^2 )   [residual identity]
  double contrib;
  {
    double q  = sh.ss.xs[tid];
    double ch = (double)chi[b*NATOM + tid];
    int z = znum[b*NATOM + tid];
    float Jr = (z == 1) ? J0 : (z == 6) ? J1 : (z == 7) ? J2 : J3;
    contrib = q*ch + (double)Jr*(double)Jr*q*q;
  }
  __syncthreads();
  sh.ss.red[tid] = contrib;
  __syncthreads();
  for (int st = 128; st > 0; st >>= 1) {
    if (tid < st) sh.ss.red[tid] += sh.ss.red[tid + st];
    __syncthreads();
  }
  if (tid == 0)
    out[NBATCH*NATOM + b] = (float)(-0.5*(sh.ss.red[0] + lam*rhsN));
}

// ---------------- host launch ----------------
extern "C" void kernel_launch(void* const* d_in, const int* in_sizes, int n_in,
                              void* d_out, int out_size, void* d_ws, size_t ws_size,
                              hipStream_t stream)
{
  // Role detection: element counts, then byte counts, then dict order.
  int iPos=-1, iCell=-1, iJ=-1, iQ=-1, cand[3]={-1,-1,-1}, nc=0;
  for (int i = 0; i < n_in; i++) {
    int s = in_sizes[i];
    if      (s == 6144) iPos  = i;
    else if (s == 72)   iCell = i;
    else if (s == 4)    iJ    = i;
    else if (s == 8)    iQ    = i;
    else if (s == 2048 && nc < 3) cand[nc++] = i;
  }
  if (!(iPos>=0 && iCell>=0 && iJ>=0 && iQ>=0 && nc>=2)) {
    iPos=iCell=iJ=iQ=-1; nc=0; cand[0]=cand[1]=cand[2]=-1;
    for (int i = 0; i < n_in; i++) {
      int s = in_sizes[i];
      if      (s == 24576) iPos  = i;
      else if (s == 288)   iCell = i;
      else if (s == 16)    iJ    = i;
      else if (s == 32)    iQ    = i;
      else if (s == 8192 && nc < 3) cand[nc++] = i;
    }
  }
  if (!(iPos>=0 && iCell>=0 && iJ>=0 && iQ>=0 && nc>=2)) {
    iPos=0; iCell=1; iJ=3; iQ=4; cand[0]=2; cand[1]=5; cand[2]=6; nc=3;
  }
  if (nc == 2) cand[2] = cand[1];

  const float* pos  = (const float*)d_in[iPos];
  const float* cell = (const float*)d_in[iCell];
  const float* Jraw = (const float*)d_in[iJ];
  const float* sysq = (const float*)d_in[iQ];
  const void*  c0   = d_in[cand[0]];
  const void*  c1   = d_in[cand[1]];
  const void*  c2   = d_in[cand[2]];
  float* out = (float*)d_out;

  char* ws = (char*)d_ws;
  double* Amat = (double*)ws;
  const size_t A_BYTES = (size_t)NBATCH*NATOM*NATOM*sizeof(double);  // 4,194,304
  double* Aug  = (double*)(ws + A_BYTES);                            // 4,243,584
  // total ws use: ~8.44 MB

  for (int t = 0; t < 16; t++)
    hipLaunchKernelGGL(build_A_k, dim3(NBATCH), dim3(256), 0, stream,
                       pos, cell, Amat, t);
  hipLaunchKernelGGL(solve_all, dim3(NBATCH), dim3(256), 0, stream,
                     Amat, Aug, pos, cell, c0, c1, c2, Jraw, sysq, out);
}

// Round 9
// 3933.074 us; speedup vs baseline: 16.3545x; 16.3545x over previous
//
#include <hip/hip_runtime.h>
#include <math.h>

#define NBATCH 8
#define NATOM  256
#define NP1    257
#define WROW   258
#define TOTALK 9261
#define KCAP   2560
#define KC     16

#define TWO_PI_D 6.283185307179586
#define DIAG_SUB 0.7978845608028654   /* 2/sqrt(2*pi) */

__device__ __constant__ int TI10[10] = {0,0,0,0,1,1,1,2,2,3};
__device__ __constant__ int TJ10[10] = {0,1,2,3,1,2,3,2,3,3};

// ---------------- shared structs ----------------
struct GemmSh {
  int4   kn[KC];                         // (n1,n2,n3,-)
  double kw[KC];                         // weight (fp64)
  double cI[KC][64], sI[KC][64];         // w-scaled I-side phases
  double cJ[KC][64], sJ[KC][64];         // J-side phases
};                                        // ~32.6 KB
struct SolveSh {
  double prow[WROW];
  double ft[NP1];
  double xs[NP1];
  double red[256];
  int    perm[NP1];
};

// ---------------- K1 (grid 8): per-atom trig tables + compact k-list ----------------
// Tg[((b*3+d)*21 + (n+10))*256 + a] = (cos(n*u_d[a]), sin(n*u_d[a])), n in [-10,10]
__global__ __launch_bounds__(256) void prep(
    const float* __restrict__ pos, const float* __restrict__ cell,
    double2* __restrict__ Tg, int4* __restrict__ klist,
    double* __restrict__ kw, int* __restrict__ kcount)
{
  const int b = blockIdx.x;
  const int tid = threadIdx.x;
  __shared__ double ivs[9];
  __shared__ double prefs;
  __shared__ int cnt;
  if (tid == 0) {
    double c[9];
#pragma unroll
    for (int i = 0; i < 9; i++) c[i] = (double)cell[b*9+i];
    double det = c[0]*(c[4]*c[8]-c[5]*c[7]) - c[1]*(c[3]*c[8]-c[5]*c[6])
               + c[2]*(c[3]*c[7]-c[4]*c[6]);
    double idet = 1.0/det;
    ivs[0]=(c[4]*c[8]-c[5]*c[7])*idet; ivs[1]=(c[2]*c[7]-c[1]*c[8])*idet; ivs[2]=(c[1]*c[5]-c[2]*c[4])*idet;
    ivs[3]=(c[5]*c[6]-c[3]*c[8])*idet; ivs[4]=(c[0]*c[8]-c[2]*c[6])*idet; ivs[5]=(c[2]*c[3]-c[0]*c[5])*idet;
    ivs[6]=(c[3]*c[7]-c[4]*c[6])*idet; ivs[7]=(c[1]*c[6]-c[0]*c[7])*idet; ivs[8]=(c[0]*c[4]-c[1]*c[3])*idet;
    prefs = 2.0*TWO_PI_D/fabs(det);      // 4*pi/V
    cnt = 0;
  }
  __syncthreads();
  // per-atom tables: 3 libm sincos + complex recurrences (full fp64)
  {
    const int a = tid;               // 256 threads = 256 atoms
    double x = (double)pos[((size_t)b*NATOM+a)*3+0];
    double y = (double)pos[((size_t)b*NATOM+a)*3+1];
    double z = (double)pos[((size_t)b*NATOM+a)*3+2];
    double u[3];
    u[0] = TWO_PI_D*(ivs[0]*x + ivs[3]*y + ivs[6]*z);
    u[1] = TWO_PI_D*(ivs[1]*x + ivs[4]*y + ivs[7]*z);
    u[2] = TWO_PI_D*(ivs[2]*x + ivs[5]*y + ivs[8]*z);
#pragma unroll
    for (int d = 0; d < 3; d++) {
      double2* T = Tg + (size_t)((b*3 + d)*21)*256;
      double c1 = cos(u[d]);
      double s1 = sin(u[d]);
      T[10*256 + a] = make_double2(1.0, 0.0);
      T[11*256 + a] = make_double2(c1,  s1);
      T[ 9*256 + a] = make_double2(c1, -s1);
      double cp = c1, sp = s1;
      for (int n = 2; n <= 10; n++) {
        double cn = cp*c1 - sp*s1;
        double sn = sp*c1 + cp*s1;
        cp = cn; sp = sn;
        T[(10+n)*256 + a] = make_double2(cp,  sp);
        T[(10-n)*256 + a] = make_double2(cp, -sp);
      }
    }
  }
  // compact half-space valid-k list
  const double ksqmax = (TWO_PI_D/1.5)*(TWO_PI_D/1.5);
  for (int m = tid; m < TOTALK; m += 256) {
    int n1 = m/441 - 10;
    int n2 = (m/21)%21 - 10;
    int n3 = m%21 - 10;
    bool half = (n1 > 0) || (n1 == 0 && (n2 > 0 || (n2 == 0 && n3 > 0)));
    if (!half) continue;
    double d1 = n1, d2 = n2, d3 = n3;
    double kx = TWO_PI_D*(ivs[0]*d1 + ivs[1]*d2 + ivs[2]*d3);
    double ky = TWO_PI_D*(ivs[3]*d1 + ivs[4]*d2 + ivs[5]*d3);
    double kz = TWO_PI_D*(ivs[6]*d1 + ivs[7]*d2 + ivs[8]*d3);
    double k2 = kx*kx + ky*ky + kz*kz;
    if (k2 > 1e-10 && k2 < ksqmax) {
      double w = 2.0 * prefs * exp(-0.5*k2) / k2;   // x2 half-space fold
      int slot = atomicAdd(&cnt, 1);
      klist[b*KCAP + slot] = make_int4(n1, n2, n3, 0);
      kw[b*KCAP + slot] = w;
    }
  }
  __syncthreads();
  if (tid == 0) kcount[b] = cnt;
}

// ---------------- fp64 tile GEMM from trig tables (no trig in hot path) ----------------
__device__ void gemm_tile(int b, int ti, int tj, int tid,
                          const double2* __restrict__ Tg,
                          const int4* __restrict__ klist,
                          const double* __restrict__ kw, int cnt,
                          double* __restrict__ A, bool mirror, GemmSh& S)
{
  const int tx = tid & 15, ty = tid >> 4;
  const int ro = ty << 2, co = tx << 2;
  double acc[16];
#pragma unroll
  for (int i = 0; i < 16; i++) acc[i] = 0.0;

  for (int k0 = 0; k0 < cnt; k0 += KC) {
    if (tid < KC) {
      int kk = k0 + tid;
      if (kk < cnt) { S.kn[tid] = klist[b*KCAP + kk]; S.kw[tid] = kw[b*KCAP + kk]; }
      else          { S.kn[tid] = make_int4(0,0,0,0); S.kw[tid] = 0.0; }
    }
    __syncthreads();
    // 2048 phase evals (2 sides x 64 atoms x KC) = 2 complex mults each
#pragma unroll
    for (int p = 0; p < 8; p++) {
      int idx = p*256 + tid;
      int a    = idx & 63;
      int kk   = (idx >> 6) & (KC-1);
      int side = idx >> 10;
      int atom = ((side == 0) ? ti : tj) + a;
      int4 nn = S.kn[kk];
      double2 t1 = Tg[(size_t)((b*3+0)*21 + (nn.x+10))*256 + atom];
      double2 t2 = Tg[(size_t)((b*3+1)*21 + (nn.y+10))*256 + atom];
      double2 t3 = Tg[(size_t)((b*3+2)*21 + (nn.z+10))*256 + atom];
      double ex = t1.x*t2.x - t1.y*t2.y;
      double ey = t1.x*t2.y + t1.y*t2.x;
      double cx = ex*t3.x - ey*t3.y;
      double cy = ex*t3.y + ey*t3.x;
      if (side == 0) { double w = S.kw[kk]; S.cI[kk][a] = w*cx; S.sI[kk][a] = w*cy; }
      else           { S.cJ[kk][a] = cx; S.sJ[kk][a] = cy; }
    }
    __syncthreads();
#pragma unroll
    for (int kk = 0; kk < KC; kk++) {
      double ci[4], si[4], cj[4], sj[4];
#pragma unroll
      for (int r = 0; r < 2; r++) {
        double2 v0 = *(const double2*)&S.cI[kk][ro + 2*r];
        ci[2*r] = v0.x; ci[2*r+1] = v0.y;
        double2 v1 = *(const double2*)&S.sI[kk][ro + 2*r];
        si[2*r] = v1.x; si[2*r+1] = v1.y;
        double2 v2 = *(const double2*)&S.cJ[kk][co + 2*r];
        cj[2*r] = v2.x; cj[2*r+1] = v2.y;
        double2 v3 = *(const double2*)&S.sJ[kk][co + 2*r];
        sj[2*r] = v3.x; sj[2*r+1] = v3.y;
      }
#pragma unroll
      for (int r = 0; r < 4; r++)
#pragma unroll
        for (int c = 0; c < 4; c++)
          acc[r*4+c] += ci[r]*cj[c] + si[r]*sj[c];
    }
    __syncthreads();
  }
#pragma unroll
  for (int r = 0; r < 4; r++) {
#pragma unroll
    for (int c = 0; c < 4; c++) {
      int gr = ti + ro + r, gc = tj + co + c;
      double v = acc[r*4+c];
      A[((size_t)b*NATOM + gr)*NATOM + gc] = v;
      if (mirror && ti != tj) A[((size_t)b*NATOM + gc)*NATOM + gr] = v;
    }
  }
  __syncthreads();
}

// ---------------- K2 (grid 80): 10 symmetric tiles x 8 batches ----------------
__global__ __launch_bounds__(256) void build_A_gemm(
    const double2* __restrict__ Tg, const int4* __restrict__ klist,
    const double* __restrict__ kw, const int* __restrict__ kcount,
    double* __restrict__ A)
{
  __shared__ GemmSh S;
  const int u = blockIdx.x;
  const int b = u / 10;
  const int t = u - b*10;
  gemm_tile(b, TI10[t]*64, TJ10[t]*64, threadIdx.x, Tg, klist, kw, kcount[b], A, true, S);
}

// ---------------- K3 (grid 8): per-tile validity check + rebuild ----------------
__global__ __launch_bounds__(256) void finish_A(
    const double2* __restrict__ Tg, const int4* __restrict__ klist,
    const double* __restrict__ kw, const int* __restrict__ kcount,
    double* __restrict__ A)
{
  __shared__ GemmSh S;
  __shared__ double red[256];
  __shared__ int bad;
  const int b = blockIdx.x;
  const int tid = threadIdx.x;
  const int cnt = kcount[b];
  for (int t = 0; t < 16; t++) {
    const int ti = (t >> 2)*64, tj = (t & 3)*64;
    double s = 0.0;
    for (int p = tid; p < 64*64; p += 256) {
      int r = p >> 6, c = p & 63;
      s += fabs(A[((size_t)b*NATOM + ti + r)*NATOM + tj + c]);
    }
    red[tid] = s;
    __syncthreads();
    for (int st = 128; st > 0; st >>= 1) {
      if (tid < st) red[tid] += red[tid + st];
      __syncthreads();
    }
    if (tid == 0) bad = !(red[0] > 1e-8 && red[0] < 1e12);
    __syncthreads();
    if (bad) gemm_tile(b, ti, tj, tid, Tg, klist, kw, cnt, A, false, S);
    __syncthreads();
  }
}

// ---------------- K4 (grid 8): monolithic solve ----------------
__global__ __launch_bounds__(256) void solve_all(
    const double* __restrict__ A, double* __restrict__ aug,
    const void* __restrict__ c0, const void* __restrict__ c1, const void* __restrict__ c2,
    const float* __restrict__ Jraw, const float* __restrict__ syschg,
    float* __restrict__ out)
{
  const int b = blockIdx.x;
  const int tid = threadIdx.x;
  const int lane = tid & 63;
  const double* Ab = A + (size_t)b*NATOM*NATOM;
  double* Pb = aug + (size_t)b*NP1*WROW;

  __shared__ SolveSh ss;
  __shared__ int pivsh;

  const float* chi = nullptr;
  const int*   znum = nullptr;
  {
    const void* cands[3] = {c0, c1, c2};
    int got = 0;
    for (int i = 0; i < 3; i++) {
      unsigned uu = ((const unsigned*)cands[i])[0];
      if (uu == 0u) continue;                                        // batch
      else if (uu < 16u) { znum = (const int*)cands[i]; got |= 1; }  // z in {1,6,7,8}
      else               { chi  = (const float*)cands[i]; got |= 2; }
    }
    if (got != 3) { chi = (const float*)c0; znum = (const int*)c1; }
  }

  const double rhsN = (double)syschg[b] * sqrt(90.0474);   // Q / NORM_FACTOR
  const float J0 = Jraw[0], J1 = Jraw[1], J2 = Jraw[2], J3 = Jraw[3];
  for (int p = tid; p < NP1*WROW; p += 256) {
    int r  = p / WROW;
    int jc = p - r*WROW;
    double v;
    if (r < NATOM) {
      if (jc < NATOM) {
        v = Ab[(size_t)r*NATOM + jc];
        if (jc == r) {
          int z = znum[b*NATOM + r];
          float Jr = (z == 1) ? J0 : (z == 6) ? J1 : (z == 7) ? J2 : J3;
          v += (double)Jr*(double)Jr - DIAG_SUB;
        }
      } else if (jc == NATOM) v = 1.0;
      else                    v = -(double)chi[b*NATOM + r];
    } else {
      v = (jc < NATOM) ? 1.0 : ((jc == NATOM) ? 0.0 : rhsN);
    }
    Pb[p] = v;
  }
  __syncthreads();

  for (int i = tid; i < NP1; i += 256) ss.perm[i] = i;
  __syncthreads();
  for (int k = 0; k < NP1; k++) {
    if (tid < 64) {
      double best = -1.0; int bi = k;
      for (int i = k + lane; i < NP1; i += 64) {
        double av = fabs(Pb[(size_t)ss.perm[i]*WROW + k]);
        if (av > best) { best = av; bi = i; }
      }
#pragma unroll
      for (int off = 32; off > 0; off >>= 1) {
        double ov = __shfl_down(best, off);
        int    oi = __shfl_down(bi, off);
        if (ov > best) { best = ov; bi = oi; }
      }
      if (lane == 0) pivsh = bi;
    }
    __syncthreads();
    if (tid == 0) {
      int pv = pivsh;
      int t = ss.perm[k]; ss.perm[k] = ss.perm[pv]; ss.perm[pv] = t;
    }
    __syncthreads();
    const size_t rowk = (size_t)ss.perm[k]*WROW;
    for (int j = k + tid; j < WROW; j += 256) ss.prow[j] = Pb[rowk + j];
    __syncthreads();
    const double dinv = 1.0 / ss.prow[k];
    for (int i = k + 1 + tid; i < NP1; i += 256)
      ss.ft[i] = Pb[(size_t)ss.perm[i]*WROW + k] * dinv;
    __syncthreads();
    for (int i = k + 1 + tid; i < NP1; i += 256) {
      const double f = ss.ft[i];
      const size_t row = (size_t)ss.perm[i]*WROW;
      for (int j = k + 1; j < WROW; j++)
        Pb[row + j] -= f * ss.prow[j];
    }
    __syncthreads();
  }

  for (int r = tid; r < NP1; r += 256)
    ss.xs[r] = Pb[(size_t)ss.perm[r]*WROW + 257];
  __syncthreads();
  for (int i = NP1 - 1; i >= 0; i--) {
    if (tid == 0) ss.xs[i] /= Pb[(size_t)ss.perm[i]*WROW + i];
    __syncthreads();
    double xi = ss.xs[i];
    for (int r = tid; r < i; r += 256)
      ss.xs[r] -= Pb[(size_t)ss.perm[r]*WROW + i] * xi;
    __syncthreads();
  }

  for (int i = tid; i < NATOM; i += 256) out[b*NATOM + i] = (float)ss.xs[i];
  const double lam = ss.xs[NATOM];
  double contrib;
  {
    double q  = ss.xs[tid];
    double ch = (double)chi[b*NATOM + tid];
    int z = znum[b*NATOM + tid];
    float Jr = (z == 1) ? J0 : (z == 6) ? J1 : (z == 7) ? J2 : J3;
    contrib = q*ch + (double)Jr*(double)Jr*q*q;
  }
  __syncthreads();
  ss.red[tid] = contrib;
  __syncthreads();
  for (int st = 128; st > 0; st >>= 1) {
    if (tid < st) ss.red[tid] += ss.red[tid + st];
    __syncthreads();
  }
  if (tid == 0)
    out[NBATCH*NATOM + b] = (float)(-0.5*(ss.red[0] + lam*rhsN));
}

// ---------------- host launch ----------------
extern "C" void kernel_launch(void* const* d_in, const int* in_sizes, int n_in,
                              void* d_out, int out_size, void* d_ws, size_t ws_size,
                              hipStream_t stream)
{
  int iPos=-1, iCell=-1, iJ=-1, iQ=-1, cand[3]={-1,-1,-1}, nc=0;
  for (int i = 0; i < n_in; i++) {
    int s = in_sizes[i];
    if      (s == 6144) iPos  = i;
    else if (s == 72)   iCell = i;
    else if (s == 4)    iJ    = i;
    else if (s == 8)    iQ    = i;
    else if (s == 2048 && nc < 3) cand[nc++] = i;
  }
  if (!(iPos>=0 && iCell>=0 && iJ>=0 && iQ>=0 && nc>=2)) {
    iPos=iCell=iJ=iQ=-1; nc=0; cand[0]=cand[1]=cand[2]=-1;
    for (int i = 0; i < n_in; i++) {
      int s = in_sizes[i];
      if      (s == 24576) iPos  = i;
      else if (s == 288)   iCell = i;
      else if (s == 16)    iJ    = i;
      else if (s == 32)    iQ    = i;
      else if (s == 8192 && nc < 3) cand[nc++] = i;
    }
  }
  if (!(iPos>=0 && iCell>=0 && iJ>=0 && iQ>=0 && nc>=2)) {
    iPos=0; iCell=1; iJ=3; iQ=4; cand[0]=2; cand[1]=5; cand[2]=6; nc=3;
  }
  if (nc == 2) cand[2] = cand[1];

  const float* pos  = (const float*)d_in[iPos];
  const float* cell = (const float*)d_in[iCell];
  const float* Jraw = (const float*)d_in[iJ];
  const float* sysq = (const float*)d_in[iQ];
  const void*  c0   = d_in[cand[0]];
  const void*  c1   = d_in[cand[1]];
  const void*  c2   = d_in[cand[2]];
  float* out = (float*)d_out;

  // ws layout (8,437,888 B total — same footprint r7 proved):
  //   Amat  [0, 4194304)
  //   Aug   [4194304, 8437888)   — used only by solve_all
  //   Tg/klist/kw/kcount alias the Aug region (dead before solve_all runs)
  char* ws = (char*)d_ws;
  double*  Amat   = (double*)ws;
  double*  Aug    = (double*)(ws + 4194304);
  double2* Tg     = (double2*)(ws + 4194304);            // 2,064,384 B
  int4*    klist  = (int4*)  (ws + 4194304 + 2064384);   //   327,680 B
  double*  kwa    = (double*)(ws + 4194304 + 2064384 + 327680);  // 163,840 B
  int*     kcount = (int*)   (ws + 4194304 + 2064384 + 327680 + 163840);

  hipLaunchKernelGGL(prep,         dim3(NBATCH), dim3(256), 0, stream,
                     pos, cell, Tg, klist, kwa, kcount);
  hipLaunchKernelGGL(build_A_gemm, dim3(80),     dim3(256), 0, stream,
                     Tg, klist, kwa, kcount, Amat);
  hipLaunchKernelGGL(finish_A,     dim3(NBATCH), dim3(256), 0, stream,
                     Tg, klist, kwa, kcount, Amat);
  hipLaunchKernelGGL(solve_all,    dim3(NBATCH), dim3(256), 0, stream,
                     Amat, Aug, c0, c1, c2, Jraw, sysq, out);
}

// Round 10
// 1573.170 us; speedup vs baseline: 40.8879x; 2.5001x over previous
//
#include <hip/hip_runtime.h>
#include <math.h>

#define NBATCH 8
#define NATOM  256
#define NP1    257
#define WROW   258
#define TOTALK 9261
#define KCAP   2560
#define KC     16
#define NB     16

#define TWO_PI_D 6.283185307179586
#define DIAG_SUB 0.7978845608028654   /* 2/sqrt(2*pi) */

__device__ __constant__ int TI10[10] = {0,0,0,0,1,1,1,2,2,3};
__device__ __constant__ int TJ10[10] = {0,1,2,3,1,2,3,2,3,3};

// ---------------- shared structs ----------------
struct GemmSh {
  int4   kn[KC];
  double kw[KC];
  double cI[KC][64], sI[KC][64];
  double cJ[KC][64], sJ[KC][64];
};

// ---------------- K1 (grid 8): per-atom trig tables + compact k-list ----------------
__global__ __launch_bounds__(256) void prep(
    const float* __restrict__ pos, const float* __restrict__ cell,
    double2* __restrict__ Tg, int4* __restrict__ klist,
    double* __restrict__ kw, int* __restrict__ kcount)
{
  const int b = blockIdx.x;
  const int tid = threadIdx.x;
  __shared__ double ivs[9];
  __shared__ double prefs;
  __shared__ int cnt;
  if (tid == 0) {
    double c[9];
#pragma unroll
    for (int i = 0; i < 9; i++) c[i] = (double)cell[b*9+i];
    double det = c[0]*(c[4]*c[8]-c[5]*c[7]) - c[1]*(c[3]*c[8]-c[5]*c[6])
               + c[2]*(c[3]*c[7]-c[4]*c[6]);
    double idet = 1.0/det;
    ivs[0]=(c[4]*c[8]-c[5]*c[7])*idet; ivs[1]=(c[2]*c[7]-c[1]*c[8])*idet; ivs[2]=(c[1]*c[5]-c[2]*c[4])*idet;
    ivs[3]=(c[5]*c[6]-c[3]*c[8])*idet; ivs[4]=(c[0]*c[8]-c[2]*c[6])*idet; ivs[5]=(c[2]*c[3]-c[0]*c[5])*idet;
    ivs[6]=(c[3]*c[7]-c[4]*c[6])*idet; ivs[7]=(c[1]*c[6]-c[0]*c[7])*idet; ivs[8]=(c[0]*c[4]-c[1]*c[3])*idet;
    prefs = 2.0*TWO_PI_D/fabs(det);
    cnt = 0;
  }
  __syncthreads();
  {
    const int a = tid;
    double x = (double)pos[((size_t)b*NATOM+a)*3+0];
    double y = (double)pos[((size_t)b*NATOM+a)*3+1];
    double z = (double)pos[((size_t)b*NATOM+a)*3+2];
    double u[3];
    u[0] = TWO_PI_D*(ivs[0]*x + ivs[3]*y + ivs[6]*z);
    u[1] = TWO_PI_D*(ivs[1]*x + ivs[4]*y + ivs[7]*z);
    u[2] = TWO_PI_D*(ivs[2]*x + ivs[5]*y + ivs[8]*z);
#pragma unroll
    for (int d = 0; d < 3; d++) {
      double2* T = Tg + (size_t)((b*3 + d)*21)*256;
      double c1 = cos(u[d]);
      double s1 = sin(u[d]);
      T[10*256 + a] = make_double2(1.0, 0.0);
      T[11*256 + a] = make_double2(c1,  s1);
      T[ 9*256 + a] = make_double2(c1, -s1);
      double cp = c1, sp = s1;
      for (int n = 2; n <= 10; n++) {
        double cn = cp*c1 - sp*s1;
        double sn = sp*c1 + cp*s1;
        cp = cn; sp = sn;
        T[(10+n)*256 + a] = make_double2(cp,  sp);
        T[(10-n)*256 + a] = make_double2(cp, -sp);
      }
    }
  }
  const double ksqmax = (TWO_PI_D/1.5)*(TWO_PI_D/1.5);
  for (int m = tid; m < TOTALK; m += 256) {
    int n1 = m/441 - 10;
    int n2 = (m/21)%21 - 10;
    int n3 = m%21 - 10;
    bool half = (n1 > 0) || (n1 == 0 && (n2 > 0 || (n2 == 0 && n3 > 0)));
    if (!half) continue;
    double d1 = n1, d2 = n2, d3 = n3;
    double kx = TWO_PI_D*(ivs[0]*d1 + ivs[1]*d2 + ivs[2]*d3);
    double ky = TWO_PI_D*(ivs[3]*d1 + ivs[4]*d2 + ivs[5]*d3);
    double kz = TWO_PI_D*(ivs[6]*d1 + ivs[7]*d2 + ivs[8]*d3);
    double k2 = kx*kx + ky*ky + kz*kz;
    if (k2 > 1e-10 && k2 < ksqmax) {
      double w = 2.0 * prefs * exp(-0.5*k2) / k2;
      int slot = atomicAdd(&cnt, 1);
      klist[b*KCAP + slot] = make_int4(n1, n2, n3, 0);
      kw[b*KCAP + slot] = w;
    }
  }
  __syncthreads();
  if (tid == 0) kcount[b] = cnt;
}

// ---------------- fp64 tile GEMM from trig tables ----------------
__device__ void gemm_tile(int b, int ti, int tj, int tid,
                          const double2* __restrict__ Tg,
                          const int4* __restrict__ klist,
                          const double* __restrict__ kw, int cnt,
                          double* __restrict__ A, bool mirror, GemmSh& S)
{
  const int tx = tid & 15, ty = tid >> 4;
  const int ro = ty << 2, co = tx << 2;
  double acc[16];
#pragma unroll
  for (int i = 0; i < 16; i++) acc[i] = 0.0;

  for (int k0 = 0; k0 < cnt; k0 += KC) {
    if (tid < KC) {
      int kk = k0 + tid;
      if (kk < cnt) { S.kn[tid] = klist[b*KCAP + kk]; S.kw[tid] = kw[b*KCAP + kk]; }
      else          { S.kn[tid] = make_int4(0,0,0,0); S.kw[tid] = 0.0; }
    }
    __syncthreads();
#pragma unroll
    for (int p = 0; p < 8; p++) {
      int idx = p*256 + tid;
      int a    = idx & 63;
      int kk   = (idx >> 6) & (KC-1);
      int side = idx >> 10;
      int atom = ((side == 0) ? ti : tj) + a;
      int4 nn = S.kn[kk];
      double2 t1 = Tg[(size_t)((b*3+0)*21 + (nn.x+10))*256 + atom];
      double2 t2 = Tg[(size_t)((b*3+1)*21 + (nn.y+10))*256 + atom];
      double2 t3 = Tg[(size_t)((b*3+2)*21 + (nn.z+10))*256 + atom];
      double ex = t1.x*t2.x - t1.y*t2.y;
      double ey = t1.x*t2.y + t1.y*t2.x;
      double cx = ex*t3.x - ey*t3.y;
      double cy = ex*t3.y + ey*t3.x;
      if (side == 0) { double w = S.kw[kk]; S.cI[kk][a] = w*cx; S.sI[kk][a] = w*cy; }
      else           { S.cJ[kk][a] = cx; S.sJ[kk][a] = cy; }
    }
    __syncthreads();
#pragma unroll
    for (int kk = 0; kk < KC; kk++) {
      double ci[4], si[4], cj[4], sj[4];
#pragma unroll
      for (int r = 0; r < 2; r++) {
        double2 v0 = *(const double2*)&S.cI[kk][ro + 2*r];
        ci[2*r] = v0.x; ci[2*r+1] = v0.y;
        double2 v1 = *(const double2*)&S.sI[kk][ro + 2*r];
        si[2*r] = v1.x; si[2*r+1] = v1.y;
        double2 v2 = *(const double2*)&S.cJ[kk][co + 2*r];
        cj[2*r] = v2.x; cj[2*r+1] = v2.y;
        double2 v3 = *(const double2*)&S.sJ[kk][co + 2*r];
        sj[2*r] = v3.x; sj[2*r+1] = v3.y;
      }
#pragma unroll
      for (int r = 0; r < 4; r++)
#pragma unroll
        for (int c = 0; c < 4; c++)
          acc[r*4+c] += ci[r]*cj[c] + si[r]*sj[c];
    }
    __syncthreads();
  }
#pragma unroll
  for (int r = 0; r < 4; r++) {
#pragma unroll
    for (int c = 0; c < 4; c++) {
      int gr = ti + ro + r, gc = tj + co + c;
      double v = acc[r*4+c];
      A[((size_t)b*NATOM + gr)*NATOM + gc] = v;
      if (mirror && ti != tj) A[((size_t)b*NATOM + gc)*NATOM + gr] = v;
    }
  }
  __syncthreads();
}

// ---------------- K2 (grid 80): 10 symmetric tiles x 8 batches ----------------
__global__ __launch_bounds__(256) void build_A_gemm(
    const double2* __restrict__ Tg, const int4* __restrict__ klist,
    const double* __restrict__ kw, const int* __restrict__ kcount,
    double* __restrict__ A)
{
  __shared__ GemmSh S;
  const int u = blockIdx.x;
  const int b = u / 10;
  const int t = u - b*10;
  gemm_tile(b, TI10[t]*64, TJ10[t]*64, threadIdx.x, Tg, klist, kw, kcount[b], A, true, S);
}

// ---------------- K3 (grid 8): per-tile validity check + rebuild ----------------
__global__ __launch_bounds__(256) void finish_A(
    const double2* __restrict__ Tg, const int4* __restrict__ klist,
    const double* __restrict__ kw, const int* __restrict__ kcount,
    double* __restrict__ A)
{
  __shared__ GemmSh S;
  __shared__ double red[256];
  __shared__ int bad;
  const int b = blockIdx.x;
  const int tid = threadIdx.x;
  const int cnt = kcount[b];
  for (int t = 0; t < 16; t++) {
    const int ti = (t >> 2)*64, tj = (t & 3)*64;
    double s = 0.0;
    for (int p = tid; p < 64*64; p += 256) {
      int r = p >> 6, c = p & 63;
      s += fabs(A[((size_t)b*NATOM + ti + r)*NATOM + tj + c]);
    }
    red[tid] = s;
    __syncthreads();
    for (int st = 128; st > 0; st >>= 1) {
      if (tid < st) red[tid] += red[tid + st];
      __syncthreads();
    }
    if (tid == 0) bad = !(red[0] > 1e-8 && red[0] < 1e12);
    __syncthreads();
    if (bad) gemm_tile(b, ti, tj, tid, Tg, klist, kw, cnt, A, false, S);
    __syncthreads();
  }
}

// ---------------- K4 (grid 8): blocked-LU solve ----------------
__global__ __launch_bounds__(256) void solve_all(
    const double* __restrict__ A, double* __restrict__ aug,
    const void* __restrict__ c0, const void* __restrict__ c1, const void* __restrict__ c2,
    const float* __restrict__ Jraw, const float* __restrict__ syschg,
    float* __restrict__ out)
{
  const int b = blockIdx.x;
  const int tid = threadIdx.x;
  const int lane = tid & 63;
  const double* Ab = A + (size_t)b*NATOM*NATOM;
  double* Pb = aug + (size_t)b*NP1*WROW;

  __shared__ double pan[NP1][18];   // panel, 16B-aligned rows (stride 18)
  __shared__ double xs[NP1];
  __shared__ double red[256];
  __shared__ int pivrel[NB];

  // classify chi / znum
  const float* chi = nullptr;
  const int*   znum = nullptr;
  {
    const void* cands[3] = {c0, c1, c2};
    int got = 0;
    for (int i = 0; i < 3; i++) {
      unsigned uu = ((const unsigned*)cands[i])[0];
      if (uu == 0u) continue;
      else if (uu < 16u) { znum = (const int*)cands[i]; got |= 1; }
      else               { chi  = (const float*)cands[i]; got |= 2; }
    }
    if (got != 3) { chi = (const float*)c0; znum = (const int*)c1; }
  }

  // build augmented system
  const double rhsN = (double)syschg[b] * sqrt(90.0474);
  const float J0 = Jraw[0], J1 = Jraw[1], J2 = Jraw[2], J3 = Jraw[3];
  for (int p = tid; p < NP1*WROW; p += 256) {
    int r  = p / WROW;
    int jc = p - r*WROW;
    double v;
    if (r < NATOM) {
      if (jc < NATOM) {
        v = Ab[(size_t)r*NATOM + jc];
        if (jc == r) {
          int z = znum[b*NATOM + r];
          float Jr = (z == 1) ? J0 : (z == 6) ? J1 : (z == 7) ? J2 : J3;
          v += (double)Jr*(double)Jr - DIAG_SUB;
        }
      } else if (jc == NATOM) v = 1.0;
      else                    v = -(double)chi[b*NATOM + r];
    } else {
      v = (jc < NATOM) ? 1.0 : ((jc == NATOM) ? 0.0 : rhsN);
    }
    Pb[p] = v;
  }
  __syncthreads();

  // -------- blocked right-looking LU with partial pivoting --------
  for (int p0 = 0; p0 < NP1; p0 += NB) {
    const int pw  = (NB < NP1 - p0) ? NB : (NP1 - p0);
    const int nr  = NP1 - p0;            // panel rows
    const int tc0 = p0 + pw;             // first trailing column
    // load panel into LDS
    for (int idx = tid; idx < nr*pw; idx += 256) {
      int r = (pw == NB) ? (idx >> 4) : (idx / pw);
      int c = (pw == NB) ? (idx & 15) : (idx - r*pw);
      pan[r][c] = Pb[(size_t)(p0+r)*WROW + p0 + c];
    }
    __syncthreads();
    // factor panel (2 barriers per column)
    for (int c = 0; c < pw; c++) {
      if (tid < 64) {
        double best = -1.0; int bi = c;
        for (int r = c + lane; r < nr; r += 64) {
          double av = fabs(pan[r][c]);
          if (av > best) { best = av; bi = r; }
        }
#pragma unroll
        for (int off = 32; off > 0; off >>= 1) {
          double ov = __shfl_down(best, off);
          int    oi = __shfl_down(bi, off);
          if (ov > best) { best = ov; bi = oi; }
        }
        int pr = __shfl(bi, 0);
        if (lane == 0) pivrel[c] = pr;
        if (pr != c && lane < pw) {
          double t = pan[c][lane]; pan[c][lane] = pan[pr][lane]; pan[pr][lane] = t;
        }
      }
      __syncthreads();
      const double dinv = 1.0 / pan[c][c];
      if (pw == NB) {
        for (int r = c + 1 + tid; r < nr; r += 256) {
          double f = pan[r][c] * dinv;
          pan[r][c] = f;
#pragma unroll
          for (int cc = c + 1; cc < NB; cc++) pan[r][cc] -= f * pan[c][cc];
        }
      } else {
        for (int r = c + 1 + tid; r < nr; r += 256) {
          double f = pan[r][c] * dinv;
          pan[r][c] = f;
          for (int cc = c + 1; cc < pw; cc++) pan[r][cc] -= f * pan[c][cc];
        }
      }
      __syncthreads();
    }
    // write panel back (barrier-free stretch from here to end of panel)
    for (int idx = tid; idx < nr*pw; idx += 256) {
      int r = (pw == NB) ? (idx >> 4) : (idx / pw);
      int c = (pw == NB) ? (idx & 15) : (idx - r*pw);
      Pb[(size_t)(p0+r)*WROW + p0 + c] = pan[r][c];
    }
    // apply row swaps to trailing columns only (each thread owns its columns
    // across ALL c, so the sequential composition is preserved per column)
    for (int c = 0; c < pw; c++) {
      int pr = pivrel[c];
      if (pr == c) continue;
      size_t ra = (size_t)(p0 + c)*WROW, rb = (size_t)(p0 + pr)*WROW;
      for (int j = tc0 + tid; j < WROW; j += 256) {
        double t1 = Pb[ra + j], t2 = Pb[rb + j];
        Pb[ra + j] = t2; Pb[rb + j] = t1;
      }
    }
    // fused TRSM + rank-pw trailing update, thread-per-column
    {
      const int j = tc0 + tid;
      if (j < WROW) {
        double v[NB];
        if (pw == NB) {
#pragma unroll
          for (int c = 0; c < NB; c++) v[c] = Pb[(size_t)(p0+c)*WROW + j];
#pragma unroll
          for (int c = 0; c < NB; c++)
#pragma unroll
            for (int r = c+1; r < NB; r++) v[r] -= pan[r][c]*v[c];
#pragma unroll
          for (int c = 0; c < NB; c++) Pb[(size_t)(p0+c)*WROW + j] = v[c];
          // trailing rows
          size_t addr = (size_t)tc0*WROW + j;
          for (int r = NB; r < nr; r++) {
            double a = Pb[addr];
#pragma unroll
            for (int m = 0; m < 8; m++) {
              double2 p2 = *(const double2*)&pan[r][2*m];
              a -= p2.x * v[2*m] + p2.y * v[2*m+1];
            }
            Pb[addr] = a; addr += WROW;
          }
        } else {
          for (int c = 0; c < pw; c++) v[c] = Pb[(size_t)(p0+c)*WROW + j];
          for (int c = 0; c < pw; c++)
            for (int r = c+1; r < pw; r++) v[r] -= pan[r][c]*v[c];
          for (int c = 0; c < pw; c++) Pb[(size_t)(p0+c)*WROW + j] = v[c];
          size_t addr = (size_t)tc0*WROW + j;
          for (int r = pw; r < nr; r++) {
            double a = Pb[addr];
            for (int c = 0; c < pw; c++) a -= pan[r][c]*v[c];
            Pb[addr] = a; addr += WROW;
          }
        }
      }
    }
    __syncthreads();   // panel LDS reused next iteration
  }

  // -------- blocked backsolve --------
  for (int r = tid; r < NP1; r += 256) xs[r] = Pb[(size_t)r*WROW + 257];
  __syncthreads();
  for (int pb0 = 256; pb0 >= 0; pb0 -= NB) {
    const int w = (pb0 == 256) ? 1 : NB;
    // load diag block into pan
    if (tid < w*w) {
      int i = tid / w, c = tid - i*w;
      pan[i][c] = Pb[(size_t)(pb0+i)*WROW + pb0 + c];
    }
    __syncthreads();
    if (tid == 0) {
      for (int i = w-1; i >= 0; i--) {
        double s = xs[pb0+i];
        for (int c = i+1; c < w; c++) s -= pan[i][c]*xs[pb0+c];
        xs[pb0+i] = s / pan[i][i];
      }
    }
    __syncthreads();
    if (tid < pb0) {
      const double* rowp = &Pb[(size_t)tid*WROW + pb0];
      double s = 0.0;
      for (int c = 0; c < w; c++) s += rowp[c]*xs[pb0+c];
      xs[tid] -= s;
    }
    __syncthreads();
  }

  // -------- outputs: q + residual-identity energy --------
  for (int i = tid; i < NATOM; i += 256) out[b*NATOM + i] = (float)xs[i];
  const double lam = xs[NATOM];
  double contrib;
  {
    double q  = xs[tid];
    double ch = (double)chi[b*NATOM + tid];
    int z = znum[b*NATOM + tid];
    float Jr = (z == 1) ? J0 : (z == 6) ? J1 : (z == 7) ? J2 : J3;
    contrib = q*ch + (double)Jr*(double)Jr*q*q;
  }
  __syncthreads();
  red[tid] = contrib;
  __syncthreads();
  for (int st = 128; st > 0; st >>= 1) {
    if (tid < st) red[tid] += red[tid + st];
    __syncthreads();
  }
  if (tid == 0)
    out[NBATCH*NATOM + b] = (float)(-0.5*(red[0] + lam*rhsN));
}

// ---------------- host launch ----------------
extern "C" void kernel_launch(void* const* d_in, const int* in_sizes, int n_in,
                              void* d_out, int out_size, void* d_ws, size_t ws_size,
                              hipStream_t stream)
{
  int iPos=-1, iCell=-1, iJ=-1, iQ=-1, cand[3]={-1,-1,-1}, nc=0;
  for (int i = 0; i < n_in; i++) {
    int s = in_sizes[i];
    if      (s == 6144) iPos  = i;
    else if (s == 72)   iCell = i;
    else if (s == 4)    iJ    = i;
    else if (s == 8)    iQ    = i;
    else if (s == 2048 && nc < 3) cand[nc++] = i;
  }
  if (!(iPos>=0 && iCell>=0 && iJ>=0 && iQ>=0 && nc>=2)) {
    iPos=iCell=iJ=iQ=-1; nc=0; cand[0]=cand[1]=cand[2]=-1;
    for (int i = 0; i < n_in; i++) {
      int s = in_sizes[i];
      if      (s == 24576) iPos  = i;
      else if (s == 288)   iCell = i;
      else if (s == 16)    iJ    = i;
      else if (s == 32)    iQ    = i;
      else if (s == 8192 && nc < 3) cand[nc++] = i;
    }
  }
  if (!(iPos>=0 && iCell>=0 && iJ>=0 && iQ>=0 && nc>=2)) {
    iPos=0; iCell=1; iJ=3; iQ=4; cand[0]=2; cand[1]=5; cand[2]=6; nc=3;
  }
  if (nc == 2) cand[2] = cand[1];

  const float* pos  = (const float*)d_in[iPos];
  const float* cell = (const float*)d_in[iCell];
  const float* Jraw = (const float*)d_in[iJ];
  const float* sysq = (const float*)d_in[iQ];
  const void*  c0   = d_in[cand[0]];
  const void*  c1   = d_in[cand[1]];
  const void*  c2   = d_in[cand[2]];
  float* out = (float*)d_out;

  // ws layout: Amat [0, 4194304) ; Aug [4194304, 8437888)
  // Tg/klist/kw/kcount alias the Aug region (dead before solve_all runs)
  char* ws = (char*)d_ws;
  double*  Amat   = (double*)ws;
  double*  Aug    = (double*)(ws + 4194304);
  double2* Tg     = (double2*)(ws + 4194304);
  int4*    klist  = (int4*)  (ws + 4194304 + 2064384);
  double*  kwa    = (double*)(ws + 4194304 + 2064384 + 327680);
  int*     kcount = (int*)   (ws + 4194304 + 2064384 + 327680 + 163840);

  hipLaunchKernelGGL(prep,         dim3(NBATCH), dim3(256), 0, stream,
                     pos, cell, Tg, klist, kwa, kcount);
  hipLaunchKernelGGL(build_A_gemm, dim3(80),     dim3(256), 0, stream,
                     Tg, klist, kwa, kcount, Amat);
  hipLaunchKernelGGL(finish_A,     dim3(NBATCH), dim3(256), 0, stream,
                     Tg, klist, kwa, kcount, Amat);
  hipLaunchKernelGGL(solve_all,    dim3(NBATCH), dim3(256), 0, stream,
                     Amat, Aug, c0, c1, c2, Jraw, sysq, out);
}

// Round 11
// 1131.280 us; speedup vs baseline: 56.8592x; 1.3906x over previous
//
#include <hip/hip_runtime.h>
#include <math.h>

#define NBATCH 8
#define NATOM  256
#define NP1    257
#define WROW   258
#define TOTALK 9261
#define KCAP   2560
#define KC     16
#define NB     16
#define BD     1024

#define TWO_PI_D 6.283185307179586
#define DIAG_SUB 0.7978845608028654   /* 2/sqrt(2*pi) */

__device__ __constant__ int TI10[10] = {0,0,0,0,1,1,1,2,2,3};
__device__ __constant__ int TJ10[10] = {0,1,2,3,1,2,3,2,3,3};

struct GemmSh {
  int4   kn[KC];
  double kw[KC];
  double cI[KC][64], sI[KC][64];
  double cJ[KC][64], sJ[KC][64];
};

// ---------------- K1 (grid 8): per-atom trig tables + compact k-list ----------------
__global__ __launch_bounds__(256) void prep(
    const float* __restrict__ pos, const float* __restrict__ cell,
    double2* __restrict__ Tg, int4* __restrict__ klist,
    double* __restrict__ kw, int* __restrict__ kcount)
{
  const int b = blockIdx.x;
  const int tid = threadIdx.x;
  __shared__ double ivs[9];
  __shared__ double prefs;
  __shared__ int cnt;
  if (tid == 0) {
    double c[9];
#pragma unroll
    for (int i = 0; i < 9; i++) c[i] = (double)cell[b*9+i];
    double det = c[0]*(c[4]*c[8]-c[5]*c[7]) - c[1]*(c[3]*c[8]-c[5]*c[6])
               + c[2]*(c[3]*c[7]-c[4]*c[6]);
    double idet = 1.0/det;
    ivs[0]=(c[4]*c[8]-c[5]*c[7])*idet; ivs[1]=(c[2]*c[7]-c[1]*c[8])*idet; ivs[2]=(c[1]*c[5]-c[2]*c[4])*idet;
    ivs[3]=(c[5]*c[6]-c[3]*c[8])*idet; ivs[4]=(c[0]*c[8]-c[2]*c[6])*idet; ivs[5]=(c[2]*c[3]-c[0]*c[5])*idet;
    ivs[6]=(c[3]*c[7]-c[4]*c[6])*idet; ivs[7]=(c[1]*c[6]-c[0]*c[7])*idet; ivs[8]=(c[0]*c[4]-c[1]*c[3])*idet;
    prefs = 2.0*TWO_PI_D/fabs(det);
    cnt = 0;
  }
  __syncthreads();
  {
    const int a = tid;
    double x = (double)pos[((size_t)b*NATOM+a)*3+0];
    double y = (double)pos[((size_t)b*NATOM+a)*3+1];
    double z = (double)pos[((size_t)b*NATOM+a)*3+2];
    double u[3];
    u[0] = TWO_PI_D*(ivs[0]*x + ivs[3]*y + ivs[6]*z);
    u[1] = TWO_PI_D*(ivs[1]*x + ivs[4]*y + ivs[7]*z);
    u[2] = TWO_PI_D*(ivs[2]*x + ivs[5]*y + ivs[8]*z);
#pragma unroll
    for (int d = 0; d < 3; d++) {
      double2* T = Tg + (size_t)((b*3 + d)*21)*256;
      double c1 = cos(u[d]);
      double s1 = sin(u[d]);
      T[10*256 + a] = make_double2(1.0, 0.0);
      T[11*256 + a] = make_double2(c1,  s1);
      T[ 9*256 + a] = make_double2(c1, -s1);
      double cp = c1, sp = s1;
      for (int n = 2; n <= 10; n++) {
        double cn = cp*c1 - sp*s1;
        double sn = sp*c1 + cp*s1;
        cp = cn; sp = sn;
        T[(10+n)*256 + a] = make_double2(cp,  sp);
        T[(10-n)*256 + a] = make_double2(cp, -sp);
      }
    }
  }
  const double ksqmax = (TWO_PI_D/1.5)*(TWO_PI_D/1.5);
  for (int m = tid; m < TOTALK; m += 256) {
    int n1 = m/441 - 10;
    int n2 = (m/21)%21 - 10;
    int n3 = m%21 - 10;
    bool half = (n1 > 0) || (n1 == 0 && (n2 > 0 || (n2 == 0 && n3 > 0)));
    if (!half) continue;
    double d1 = n1, d2 = n2, d3 = n3;
    double kx = TWO_PI_D*(ivs[0]*d1 + ivs[1]*d2 + ivs[2]*d3);
    double ky = TWO_PI_D*(ivs[3]*d1 + ivs[4]*d2 + ivs[5]*d3);
    double kz = TWO_PI_D*(ivs[6]*d1 + ivs[7]*d2 + ivs[8]*d3);
    double k2 = kx*kx + ky*ky + kz*kz;
    if (k2 > 1e-10 && k2 < ksqmax) {
      double w = 2.0 * prefs * exp(-0.5*k2) / k2;
      int slot = atomicAdd(&cnt, 1);
      klist[b*KCAP + slot] = make_int4(n1, n2, n3, 0);
      kw[b*KCAP + slot] = w;
    }
  }
  __syncthreads();
  if (tid == 0) kcount[b] = cnt;
}

// ---------------- fp64 tile GEMM from trig tables, k range [ks,ke) ----------------
__device__ void gemm_tile(int b, int ti, int tj, int tid,
                          const double2* __restrict__ Tg,
                          const int4* __restrict__ klist,
                          const double* __restrict__ kw, int ks, int ke,
                          double* __restrict__ A, bool mirror, GemmSh& S)
{
  const int tx = tid & 15, ty = tid >> 4;
  const int ro = ty << 2, co = tx << 2;
  double acc[16];
#pragma unroll
  for (int i = 0; i < 16; i++) acc[i] = 0.0;

  for (int k0 = ks; k0 < ke; k0 += KC) {
    if (tid < KC) {
      int kk = k0 + tid;
      if (kk < ke) { S.kn[tid] = klist[b*KCAP + kk]; S.kw[tid] = kw[b*KCAP + kk]; }
      else         { S.kn[tid] = make_int4(0,0,0,0); S.kw[tid] = 0.0; }
    }
    __syncthreads();
#pragma unroll
    for (int p = 0; p < 8; p++) {
      int idx = p*256 + tid;
      int a    = idx & 63;
      int kk   = (idx >> 6) & (KC-1);
      int side = idx >> 10;
      int atom = ((side == 0) ? ti : tj) + a;
      int4 nn = S.kn[kk];
      double2 t1 = Tg[(size_t)((b*3+0)*21 + (nn.x+10))*256 + atom];
      double2 t2 = Tg[(size_t)((b*3+1)*21 + (nn.y+10))*256 + atom];
      double2 t3 = Tg[(size_t)((b*3+2)*21 + (nn.z+10))*256 + atom];
      double ex = t1.x*t2.x - t1.y*t2.y;
      double ey = t1.x*t2.y + t1.y*t2.x;
      double cx = ex*t3.x - ey*t3.y;
      double cy = ex*t3.y + ey*t3.x;
      if (side == 0) { double w = S.kw[kk]; S.cI[kk][a] = w*cx; S.sI[kk][a] = w*cy; }
      else           { S.cJ[kk][a] = cx; S.sJ[kk][a] = cy; }
    }
    __syncthreads();
#pragma unroll
    for (int kk = 0; kk < KC; kk++) {
      double ci[4], si[4], cj[4], sj[4];
#pragma unroll
      for (int r = 0; r < 2; r++) {
        double2 v0 = *(const double2*)&S.cI[kk][ro + 2*r];
        ci[2*r] = v0.x; ci[2*r+1] = v0.y;
        double2 v1 = *(const double2*)&S.sI[kk][ro + 2*r];
        si[2*r] = v1.x; si[2*r+1] = v1.y;
        double2 v2 = *(const double2*)&S.cJ[kk][co + 2*r];
        cj[2*r] = v2.x; cj[2*r+1] = v2.y;
        double2 v3 = *(const double2*)&S.sJ[kk][co + 2*r];
        sj[2*r] = v3.x; sj[2*r+1] = v3.y;
      }
#pragma unroll
      for (int r = 0; r < 4; r++)
#pragma unroll
        for (int c = 0; c < 4; c++)
          acc[r*4+c] += ci[r]*cj[c] + si[r]*sj[c];
    }
    __syncthreads();
  }
#pragma unroll
  for (int r = 0; r < 4; r++) {
#pragma unroll
    for (int c = 0; c < 4; c++) {
      int gr = ti + ro + r, gc = tj + co + c;
      double v = acc[r*4+c];
      A[((size_t)b*NATOM + gr)*NATOM + gc] = v;
      if (mirror && ti != tj) A[((size_t)b*NATOM + gc)*NATOM + gr] = v;
    }
  }
  __syncthreads();
}

// ---------------- K2 (grid 80*nsplit): 10 tiles x 8 batches x k-splits ----------------
__global__ __launch_bounds__(256) void build_A_gemm(
    const double2* __restrict__ Tg, const int4* __restrict__ klist,
    const double* __restrict__ kw, const int* __restrict__ kcount,
    double* __restrict__ A, int nsplit)
{
  __shared__ GemmSh S;
  const int u = blockIdx.x;
  const int s = u / 80;
  const int r = u - s*80;
  const int b = r / 10;
  const int t = r - b*10;
  const int cnt = kcount[b];
  const int ks = (int)((long long)cnt * s / nsplit);
  const int ke = (int)((long long)cnt * (s+1) / nsplit);
  double* plane = A + (size_t)s*NBATCH*NATOM*NATOM;
  gemm_tile(b, TI10[t]*64, TJ10[t]*64, threadIdx.x, Tg, klist, kw, ks, ke, plane, true, S);
}

// ---------------- K3 (grid 8): sampled validity check + per-plane-tile rebuild ----------------
__global__ __launch_bounds__(256) void finish_A(
    const double2* __restrict__ Tg, const int4* __restrict__ klist,
    const double* __restrict__ kw, const int* __restrict__ kcount,
    double* __restrict__ A, int nsplit)
{
  __shared__ GemmSh S;
  __shared__ double red[256];
  __shared__ int bad;
  const int b = blockIdx.x;
  const int tid = threadIdx.x;
  const int cnt = kcount[b];
  for (int s = 0; s < nsplit; s++) {
    const int ks = (int)((long long)cnt * s / nsplit);
    const int ke = (int)((long long)cnt * (s+1) / nsplit);
    double* plane = A + (size_t)s*NBATCH*NATOM*NATOM;
    for (int t = 0; t < 16; t++) {
      const int ti = (t >> 2)*64, tj = (t & 3)*64;
      // 256-point sample of the 64x64 tile
      int p = tid*16;
      int r = p >> 6, c = p & 63;
      double v = plane[((size_t)b*NATOM + ti + r)*NATOM + tj + c];
      red[tid] = fabs(v);
      __syncthreads();
      for (int st = 128; st > 0; st >>= 1) {
        if (tid < st) red[tid] += red[tid + st];
        __syncthreads();
      }
      if (tid == 0) bad = !(red[0] > 1e-15 && red[0] < 1e12);
      __syncthreads();
      if (bad) gemm_tile(b, ti, tj, tid, Tg, klist, kw, ks, ke, plane, false, S);
      __syncthreads();
    }
  }
}

// ---------------- K4 (grid 8, block 1024): blocked-LU solve ----------------
__global__ __launch_bounds__(BD) void solve_all(
    const double* __restrict__ A, int nsplit, double* __restrict__ aug,
    const void* __restrict__ c0, const void* __restrict__ c1, const void* __restrict__ c2,
    const float* __restrict__ Jraw, const float* __restrict__ syschg,
    float* __restrict__ out)
{
  const int b = blockIdx.x;
  const int tid = threadIdx.x;
  const int lane = tid & 63;
  const size_t planeSz = (size_t)NBATCH*NATOM*NATOM;
  const double* Ab0 = A + (size_t)b*NATOM*NATOM;
  double* Pb = aug + (size_t)b*NP1*WROW;

  __shared__ double pan[NP1][18];     // panel (row stride 18 doubles)
  __shared__ double Ub[NB][256];      // TRSM result block
  __shared__ double xs[NP1];
  __shared__ double red[BD];
  __shared__ int pivrel[NB];

  // classify chi / znum
  const float* chi = nullptr;
  const int*   znum = nullptr;
  {
    const void* cands[3] = {c0, c1, c2};
    int got = 0;
    for (int i = 0; i < 3; i++) {
      unsigned uu = ((const unsigned*)cands[i])[0];
      if (uu == 0u) continue;
      else if (uu < 16u) { znum = (const int*)cands[i]; got |= 1; }
      else               { chi  = (const float*)cands[i]; got |= 2; }
    }
    if (got != 3) { chi = (const float*)c0; znum = (const int*)c1; }
  }

  // build augmented system (sum k-split planes)
  const double rhsN = (double)syschg[b] * sqrt(90.0474);
  const float J0 = Jraw[0], J1 = Jraw[1], J2 = Jraw[2], J3 = Jraw[3];
  for (int p = tid; p < NP1*WROW; p += BD) {
    int r  = p / WROW;
    int jc = p - r*WROW;
    double v;
    if (r < NATOM) {
      if (jc < NATOM) {
        v = Ab0[(size_t)r*NATOM + jc];
        if (nsplit > 1) v += Ab0[planeSz + (size_t)r*NATOM + jc];
        if (jc == r) {
          int z = znum[b*NATOM + r];
          float Jr = (z == 1) ? J0 : (z == 6) ? J1 : (z == 7) ? J2 : J3;
          v += (double)Jr*(double)Jr - DIAG_SUB;
        }
      } else if (jc == NATOM) v = 1.0;
      else                    v = -(double)chi[b*NATOM + r];
    } else {
      v = (jc < NATOM) ? 1.0 : ((jc == NATOM) ? 0.0 : rhsN);
    }
    Pb[p] = v;
  }
  __syncthreads();

  // -------- blocked right-looking LU with partial pivoting --------
  for (int p0 = 0; p0 < NP1; p0 += NB) {
    const int pw  = (NB < NP1 - p0) ? NB : (NP1 - p0);
    const int nr  = NP1 - p0;
    const int nrt = nr - pw;             // trailing rows
    const int tc0 = p0 + pw;
    const int tc  = WROW - tc0;          // trailing cols (<= 242)
    // load panel into LDS
    for (int idx = tid; idx < nr*pw; idx += BD) {
      int r = (pw == NB) ? (idx >> 4) : (idx / pw);
      int c = (pw == NB) ? (idx & 15) : (idx - r*pw);
      pan[r][c] = Pb[(size_t)(p0+r)*WROW + p0 + c];
    }
    __syncthreads();
    // factor panel
    for (int c = 0; c < pw; c++) {
      if (tid < 64) {
        double best = -1.0; int bi = c;
        for (int r = c + lane; r < nr; r += 64) {
          double av = fabs(pan[r][c]);
          if (av > best) { best = av; bi = r; }
        }
#pragma unroll
        for (int off = 32; off > 0; off >>= 1) {
          double ov = __shfl_down(best, off);
          int    oi = __shfl_down(bi, off);
          if (ov > best) { best = ov; bi = oi; }
        }
        int pr = __shfl(bi, 0);
        if (lane == 0) pivrel[c] = pr;
        if (pr != c && lane < pw) {
          double t = pan[c][lane]; pan[c][lane] = pan[pr][lane]; pan[pr][lane] = t;
        }
      }
      __syncthreads();
      const double dinv = 1.0 / pan[c][c];
      for (int r = c + 1 + tid; r < nr; r += BD) {
        double f = pan[r][c] * dinv;
        pan[r][c] = f;
        if (pw == NB) {
#pragma unroll
          for (int cc = c + 1; cc < NB; cc++) pan[r][cc] -= f * pan[c][cc];
        } else {
          for (int cc = c + 1; cc < pw; cc++) pan[r][cc] -= f * pan[c][cc];
        }
      }
      __syncthreads();
    }
    // write L/U panel back
    for (int idx = tid; idx < nr*pw; idx += BD) {
      int r = (pw == NB) ? (idx >> 4) : (idx / pw);
      int c = (pw == NB) ? (idx & 15) : (idx - r*pw);
      Pb[(size_t)(p0+r)*WROW + p0 + c] = pan[r][c];
    }
    // apply row swaps to trailing columns (thread-owns-column across all c)
    for (int c = 0; c < pw; c++) {
      int pr = pivrel[c];
      if (pr == c) continue;
      size_t ra = (size_t)(p0 + c)*WROW, rb = (size_t)(p0 + pr)*WROW;
      for (int j = tc0 + tid; j < WROW; j += BD) {
        double t1 = Pb[ra + j], t2 = Pb[rb + j];
        Pb[ra + j] = t2; Pb[rb + j] = t1;
      }
    }
    __syncthreads();
    // TRSM (thread-per-column) -> Ub in LDS + write U rows back
    if (pw == NB) {
      if (tid < tc) {
        const int j = tc0 + tid;
        double v[NB];
#pragma unroll
        for (int c = 0; c < NB; c++) v[c] = Pb[(size_t)(p0+c)*WROW + j];
#pragma unroll
        for (int c = 0; c < NB; c++)
#pragma unroll
          for (int r = c+1; r < NB; r++) v[r] -= pan[r][c]*v[c];
#pragma unroll
        for (int c = 0; c < NB; c++) {
          Pb[(size_t)(p0+c)*WROW + j] = v[c];
          Ub[c][tid] = v[c];
        }
      }
      __syncthreads();
      // 2-D trailing update: thread (jt, rgroup) walks rows stride 4
      {
        const int jt = tid & 255;
        const int rgroup = tid >> 8;
        if (jt < tc) {
          double v[NB];
#pragma unroll
          for (int c = 0; c < NB; c++) v[c] = Ub[c][jt];
          for (int rr = rgroup; rr < nrt; rr += 4) {
            const size_t addr = (size_t)(tc0 + rr)*WROW + tc0 + jt;
            double a = Pb[addr];
#pragma unroll
            for (int m = 0; m < 8; m++) {
              double2 p2 = *(const double2*)&pan[NB+rr][2*m];
              a -= p2.x * v[2*m] + p2.y * v[2*m+1];
            }
            Pb[addr] = a;
          }
        }
      }
    } else {
      // last panel (pw < NB): tiny scalar TRSM, no trailing rows
      if (tid < tc) {
        const int j = tc0 + tid;
        double v[NB];
        for (int c = 0; c < pw; c++) v[c] = Pb[(size_t)(p0+c)*WROW + j];
        for (int c = 0; c < pw; c++)
          for (int r = c+1; r < pw; r++) v[r] -= pan[r][c]*v[c];
        for (int c = 0; c < pw; c++) Pb[(size_t)(p0+c)*WROW + j] = v[c];
      }
    }
    __syncthreads();
  }

  // -------- blocked backsolve --------
  for (int r = tid; r < NP1; r += BD) xs[r] = Pb[(size_t)r*WROW + 257];
  __syncthreads();
  for (int pb0 = 256; pb0 >= 0; pb0 -= NB) {
    const int w = (pb0 == 256) ? 1 : NB;
    if (tid < w*w) {
      int i = tid / w, c = tid - i*w;
      pan[i][c] = Pb[(size_t)(pb0+i)*WROW + pb0 + c];
    }
    __syncthreads();
    if (tid == 0) {
      for (int i = w-1; i >= 0; i--) {
        double s = xs[pb0+i];
        for (int c = i+1; c < w; c++) s -= pan[i][c]*xs[pb0+c];
        xs[pb0+i] = s / pan[i][i];
      }
    }
    __syncthreads();
    if (tid < pb0) {
      const double* rowp = &Pb[(size_t)tid*WROW + pb0];
      double s = 0.0;
      for (int c = 0; c < w; c++) s += rowp[c]*xs[pb0+c];
      xs[tid] -= s;
    }
    __syncthreads();
  }

  // -------- outputs: q + residual-identity energy --------
  for (int i = tid; i < NATOM; i += BD) out[b*NATOM + i] = (float)xs[i];
  const double lam = xs[NATOM];
  double contrib = 0.0;
  if (tid < NATOM) {
    double q  = xs[tid];
    double ch = (double)chi[b*NATOM + tid];
    int z = znum[b*NATOM + tid];
    float Jr = (z == 1) ? J0 : (z == 6) ? J1 : (z == 7) ? J2 : J3;
    contrib = q*ch + (double)Jr*(double)Jr*q*q;
  }
  __syncthreads();
  red[tid] = contrib;
  __syncthreads();
  for (int st = BD/2; st > 0; st >>= 1) {
    if (tid < st) red[tid] += red[tid + st];
    __syncthreads();
  }
  if (tid == 0)
    out[NBATCH*NATOM + b] = (float)(-0.5*(red[0] + lam*rhsN));
}

// ---------------- host launch ----------------
extern "C" void kernel_launch(void* const* d_in, const int* in_sizes, int n_in,
                              void* d_out, int out_size, void* d_ws, size_t ws_size,
                              hipStream_t stream)
{
  int iPos=-1, iCell=-1, iJ=-1, iQ=-1, cand[3]={-1,-1,-1}, nc=0;
  for (int i = 0; i < n_in; i++) {
    int s = in_sizes[i];
    if      (s == 6144) iPos  = i;
    else if (s == 72)   iCell = i;
    else if (s == 4)    iJ    = i;
    else if (s == 8)    iQ    = i;
    else if (s == 2048 && nc < 3) cand[nc++] = i;
  }
  if (!(iPos>=0 && iCell>=0 && iJ>=0 && iQ>=0 && nc>=2)) {
    iPos=iCell=iJ=iQ=-1; nc=0; cand[0]=cand[1]=cand[2]=-1;
    for (int i = 0; i < n_in; i++) {
      int s = in_sizes[i];
      if      (s == 24576) iPos  = i;
      else if (s == 288)   iCell = i;
      else if (s == 16)    iJ    = i;
      else if (s == 32)    iQ    = i;
      else if (s == 8192 && nc < 3) cand[nc++] = i;
    }
  }
  if (!(iPos>=0 && iCell>=0 && iJ>=0 && iQ>=0 && nc>=2)) {
    iPos=0; iCell=1; iJ=3; iQ=4; cand[0]=2; cand[1]=5; cand[2]=6; nc=3;
  }
  if (nc == 2) cand[2] = cand[1];

  const float* pos  = (const float*)d_in[iPos];
  const float* cell = (const float*)d_in[iCell];
  const float* Jraw = (const float*)d_in[iJ];
  const float* sysq = (const float*)d_in[iQ];
  const void*  c0   = d_in[cand[0]];
  const void*  c1   = d_in[cand[1]];
  const void*  c2   = d_in[cand[2]];
  float* out = (float*)d_out;

  // ws layout: [A planes (nsplit x 4 MB)] [Aug 4.24 MB, aliased by Tg/klist/kw/kcount]
  const size_t planeB = 4194304, augB = 4243584;
  int nsplit = (ws_size >= 2*planeB + augB) ? 2 : 1;
  char* ws = (char*)d_ws;
  double*  Amat   = (double*)ws;
  char*    augBase = ws + (size_t)nsplit*planeB;
  double*  Aug    = (double*)augBase;
  double2* Tg     = (double2*)augBase;
  int4*    klist  = (int4*)  (augBase + 2064384);
  double*  kwa    = (double*)(augBase + 2064384 + 327680);
  int*     kcount = (int*)   (augBase + 2064384 + 327680 + 163840);

  hipLaunchKernelGGL(prep,         dim3(NBATCH),    dim3(256), 0, stream,
                     pos, cell, Tg, klist, kwa, kcount);
  hipLaunchKernelGGL(build_A_gemm, dim3(80*nsplit), dim3(256), 0, stream,
                     Tg, klist, kwa, kcount, Amat, nsplit);
  hipLaunchKernelGGL(finish_A,     dim3(NBATCH),    dim3(256), 0, stream,
                     Tg, klist, kwa, kcount, Amat, nsplit);
  hipLaunchKernelGGL(solve_all,    dim3(NBATCH),    dim3(BD),  0, stream,
                     Amat, nsplit, Aug, c0, c1, c2, Jraw, sysq, out);
}

// Round 13
// 1101.352 us; speedup vs baseline: 58.4042x; 1.0272x over previous
//
#include <hip/hip_runtime.h>
#include <math.h>

#define NBATCH 8
#define NATOM  256
#define NP1    257
#define WROW   258
#define TOTALK 9261
#define KCAP   2560
#define KC     16
#define NB     16
#define BD     1024

#define TWO_PI_D 6.283185307179586
#define DIAG_SUB 0.7978845608028654   /* 2/sqrt(2*pi) */

__device__ __constant__ int TI10[10] = {0,0,0,0,1,1,1,2,2,3};
__device__ __constant__ int TJ10[10] = {0,1,2,3,1,2,3,2,3,3};

struct GemmSh {
  int4   kn[KC];
  double kw[KC];
  double cI[KC][64], sI[KC][64];
  double cJ[KC][64], sJ[KC][64];
};

__device__ __forceinline__ void classify2(const void* c0, const void* c1, const void* c2,
                                          const float*& chi, const int*& znum)
{
  const void* cands[3] = {c0, c1, c2};
  int got = 0;
  for (int i = 0; i < 3; i++) {
    unsigned uu = ((const unsigned*)cands[i])[0];
    if (uu == 0u) continue;                                      // batch
    else if (uu < 16u) { znum = (const int*)cands[i]; got |= 1; }// z in {1,6,7,8}
    else               { chi  = (const float*)cands[i]; got |= 2; }
  }
  if (got != 3) { chi = (const float*)c0; znum = (const int*)c1; }
}

// ---------------- K1 (grid 8): trig tables + k-list + aug borders ----------------
__global__ __launch_bounds__(256) void prep(
    const float* __restrict__ pos, const float* __restrict__ cell,
    double2* __restrict__ Tg, int4* __restrict__ klist,
    double* __restrict__ kw, int* __restrict__ kcount,
    const void* __restrict__ c0, const void* __restrict__ c1, const void* __restrict__ c2,
    const float* __restrict__ syschg,
    double* __restrict__ P0g, double* __restrict__ P1g, int nplanes)
{
  const int b = blockIdx.x;
  const int tid = threadIdx.x;
  __shared__ double ivs[9];
  __shared__ double prefs;
  __shared__ int cnt;
  if (tid == 0) {
    double c[9];
#pragma unroll
    for (int i = 0; i < 9; i++) c[i] = (double)cell[b*9+i];
    double det = c[0]*(c[4]*c[8]-c[5]*c[7]) - c[1]*(c[3]*c[8]-c[5]*c[6])
               + c[2]*(c[3]*c[7]-c[4]*c[6]);
    double idet = 1.0/det;
    ivs[0]=(c[4]*c[8]-c[5]*c[7])*idet; ivs[1]=(c[2]*c[7]-c[1]*c[8])*idet; ivs[2]=(c[1]*c[5]-c[2]*c[4])*idet;
    ivs[3]=(c[5]*c[6]-c[3]*c[8])*idet; ivs[4]=(c[0]*c[8]-c[2]*c[6])*idet; ivs[5]=(c[2]*c[3]-c[0]*c[5])*idet;
    ivs[6]=(c[3]*c[7]-c[4]*c[6])*idet; ivs[7]=(c[1]*c[6]-c[0]*c[7])*idet; ivs[8]=(c[0]*c[4]-c[1]*c[3])*idet;
    prefs = 2.0*TWO_PI_D/fabs(det);
    cnt = 0;
  }
  __syncthreads();
  {
    const int a = tid;
    double x = (double)pos[((size_t)b*NATOM+a)*3+0];
    double y = (double)pos[((size_t)b*NATOM+a)*3+1];
    double z = (double)pos[((size_t)b*NATOM+a)*3+2];
    double u[3];
    u[0] = TWO_PI_D*(ivs[0]*x + ivs[3]*y + ivs[6]*z);
    u[1] = TWO_PI_D*(ivs[1]*x + ivs[4]*y + ivs[7]*z);
    u[2] = TWO_PI_D*(ivs[2]*x + ivs[5]*y + ivs[8]*z);
#pragma unroll
    for (int d = 0; d < 3; d++) {
      double2* T = Tg + (size_t)((b*3 + d)*21)*256;
      double c1 = cos(u[d]);
      double s1 = sin(u[d]);
      T[10*256 + a] = make_double2(1.0, 0.0);
      T[11*256 + a] = make_double2(c1,  s1);
      T[ 9*256 + a] = make_double2(c1, -s1);
      double cp = c1, sp = s1;
      for (int n = 2; n <= 10; n++) {
        double cn = cp*c1 - sp*s1;
        double sn = sp*c1 + cp*s1;
        cp = cn; sp = sn;
        T[(10+n)*256 + a] = make_double2(cp,  sp);
        T[(10-n)*256 + a] = make_double2(cp, -sp);
      }
    }
  }
  const double ksqmax = (TWO_PI_D/1.5)*(TWO_PI_D/1.5);
  for (int m = tid; m < TOTALK; m += 256) {
    int n1 = m/441 - 10;
    int n2 = (m/21)%21 - 10;
    int n3 = m%21 - 10;
    bool half = (n1 > 0) || (n1 == 0 && (n2 > 0 || (n2 == 0 && n3 > 0)));
    if (!half) continue;
    double d1 = n1, d2 = n2, d3 = n3;
    double kx = TWO_PI_D*(ivs[0]*d1 + ivs[1]*d2 + ivs[2]*d3);
    double ky = TWO_PI_D*(ivs[3]*d1 + ivs[4]*d2 + ivs[5]*d3);
    double kz = TWO_PI_D*(ivs[6]*d1 + ivs[7]*d2 + ivs[8]*d3);
    double k2 = kx*kx + ky*ky + kz*kz;
    if (k2 > 1e-10 && k2 < ksqmax) {
      double w = 2.0 * prefs * exp(-0.5*k2) / k2;
      int slot = atomicAdd(&cnt, 1);
      klist[b*KCAP + slot] = make_int4(n1, n2, n3, 0);
      kw[b*KCAP + slot] = w;
    }
  }
  // aug borders (plane0 real values, plane1 zeros)
  {
    const float* chi = nullptr; const int* znum = nullptr;
    classify2(c0, c1, c2, chi, znum);
    double* P0b = P0g + (size_t)b*NP1*WROW;
    double* P1b = P1g + (size_t)b*NP1*WROW;
    for (int i = tid; i < NATOM; i += 256) {
      P0b[(size_t)NATOM*WROW + i] = 1.0;                 // bottom row
      P0b[(size_t)i*WROW + NATOM] = 1.0;                 // right col
      P0b[(size_t)i*WROW + 257]   = -(double)chi[b*NATOM + i];  // rhs
      if (nplanes > 1) {
        P1b[(size_t)NATOM*WROW + i] = 0.0;
        P1b[(size_t)i*WROW + NATOM] = 0.0;
        P1b[(size_t)i*WROW + 257]   = 0.0;
      }
    }
    if (tid == 0) {
      P0b[(size_t)NATOM*WROW + NATOM] = 0.0;
      P0b[(size_t)NATOM*WROW + 257]   = (double)syschg[b]*sqrt(90.0474);
      if (nplanes > 1) {
        P1b[(size_t)NATOM*WROW + NATOM] = 0.0;
        P1b[(size_t)NATOM*WROW + 257]   = 0.0;
      }
    }
  }
  __syncthreads();
  if (tid == 0) kcount[b] = cnt;
}

// ---------------- fp64 tile GEMM into aug-geometry plane ----------------
__device__ void gemm_tile(int b, int ti, int tj, int tid,
                          const double2* __restrict__ Tg,
                          const int4* __restrict__ klist,
                          const double* __restrict__ kw, int ks, int ke,
                          double* __restrict__ Ab, bool mirror, GemmSh& S)
{
  const int tx = tid & 15, ty = tid >> 4;
  const int ro = ty << 2, co = tx << 2;
  double acc[16];
#pragma unroll
  for (int i = 0; i < 16; i++) acc[i] = 0.0;

  for (int k0 = ks; k0 < ke; k0 += KC) {
    if (tid < KC) {
      int kk = k0 + tid;
      if (kk < ke) { S.kn[tid] = klist[b*KCAP + kk]; S.kw[tid] = kw[b*KCAP + kk]; }
      else         { S.kn[tid] = make_int4(0,0,0,0); S.kw[tid] = 0.0; }
    }
    __syncthreads();
#pragma unroll
    for (int p = 0; p < 8; p++) {
      int idx = p*256 + tid;
      int a    = idx & 63;
      int kk   = (idx >> 6) & (KC-1);
      int side = idx >> 10;
      int atom = ((side == 0) ? ti : tj) + a;
      int4 nn = S.kn[kk];
      double2 t1 = Tg[(size_t)((b*3+0)*21 + (nn.x+10))*256 + atom];
      double2 t2 = Tg[(size_t)((b*3+1)*21 + (nn.y+10))*256 + atom];
      double2 t3 = Tg[(size_t)((b*3+2)*21 + (nn.z+10))*256 + atom];
      double ex = t1.x*t2.x - t1.y*t2.y;
      double ey = t1.x*t2.y + t1.y*t2.x;
      double cx = ex*t3.x - ey*t3.y;
      double cy = ex*t3.y + ey*t3.x;
      if (side == 0) { double w = S.kw[kk]; S.cI[kk][a] = w*cx; S.sI[kk][a] = w*cy; }
      else           { S.cJ[kk][a] = cx; S.sJ[kk][a] = cy; }
    }
    __syncthreads();
#pragma unroll
    for (int kk = 0; kk < KC; kk++) {
      double ci[4], si[4], cj[4], sj[4];
#pragma unroll
      for (int r = 0; r < 2; r++) {
        double2 v0 = *(const double2*)&S.cI[kk][ro + 2*r];
        ci[2*r] = v0.x; ci[2*r+1] = v0.y;
        double2 v1 = *(const double2*)&S.sI[kk][ro + 2*r];
        si[2*r] = v1.x; si[2*r+1] = v1.y;
        double2 v2 = *(const double2*)&S.cJ[kk][co + 2*r];
        cj[2*r] = v2.x; cj[2*r+1] = v2.y;
        double2 v3 = *(const double2*)&S.sJ[kk][co + 2*r];
        sj[2*r] = v3.x; sj[2*r+1] = v3.y;
      }
#pragma unroll
      for (int r = 0; r < 4; r++)
#pragma unroll
        for (int c = 0; c < 4; c++)
          acc[r*4+c] += ci[r]*cj[c] + si[r]*sj[c];
    }
    __syncthreads();
  }
#pragma unroll
  for (int r = 0; r < 4; r++) {
#pragma unroll
    for (int c = 0; c < 4; c++) {
      int gr = ti + ro + r, gc = tj + co + c;
      double v = acc[r*4+c];
      Ab[(size_t)gr*WROW + gc] = v;
      if (mirror && ti != tj) Ab[(size_t)gc*WROW + gr] = v;
    }
  }
  __syncthreads();
}

// ---------------- K2 (grid 80*nplanes): tiles x batches x k-splits ----------------
__global__ __launch_bounds__(256) void build_A_gemm(
    const double2* __restrict__ Tg, const int4* __restrict__ klist,
    const double* __restrict__ kw, const int* __restrict__ kcount,
    double* __restrict__ P0g, double* __restrict__ P1g, int nplanes)
{
  __shared__ GemmSh S;
  const int u = blockIdx.x;
  const int s = u / 80;
  const int r = u - s*80;
  const int b = r / 10;
  const int t = r - b*10;
  const int cnt = kcount[b];
  const int ks = (int)((long long)cnt * s / nplanes);
  const int ke = (int)((long long)cnt * (s+1) / nplanes);
  double* Ab = ((s == 0) ? P0g : P1g) + (size_t)b*NP1*WROW;
  gemm_tile(b, TI10[t]*64, TJ10[t]*64, threadIdx.x, Tg, klist, kw, ks, ke, Ab, true, S);
}

// ---------------- K3 (grid 8): exact-poison tile check + rebuild ----------------
__global__ __launch_bounds__(256) void finish_A(
    const double2* __restrict__ Tg, const int4* __restrict__ klist,
    const double* __restrict__ kw, const int* __restrict__ kcount,
    double* __restrict__ P0g, double* __restrict__ P1g, int nplanes)
{
  __shared__ GemmSh S;
  const int b = blockIdx.x;
  const int tid = threadIdx.x;
  const int cnt = kcount[b];
  for (int s = 0; s < nplanes; s++) {
    const int ks = (int)((long long)cnt * s / nplanes);
    const int ke = (int)((long long)cnt * (s+1) / nplanes);
    double* Ab = ((s == 0) ? P0g : P1g) + (size_t)b*NP1*WROW;
    for (int t = 0; t < 16; t++) {
      const int ti = (t >> 2)*64, tj = (t & 3)*64;
      int bad = 0;
#pragma unroll
      for (int k = 0; k < 8; k++) {
        int p = (tid << 4) + k;
        int r = p >> 6, c = p & 63;
        double v = Ab[(size_t)(ti+r)*WROW + tj + c];
        if (__double_as_longlong(v) == (long long)0xAAAAAAAAAAAAAAAAULL) bad = 1;
      }
      if (__syncthreads_or(bad))
        gemm_tile(b, ti, tj, tid, Tg, klist, kw, ks, ke, Ab, false, S);
      __syncthreads();
    }
  }
}

// ---------------- K4 (grid 8, block 1024): LU solve, virtual pivoting ----------------
__global__ __launch_bounds__(BD) void solve_all(
    double* __restrict__ P0g, const double* __restrict__ P1g, int nplanes,
    const void* __restrict__ c0, const void* __restrict__ c1, const void* __restrict__ c2,
    const float* __restrict__ Jraw, const float* __restrict__ syschg,
    float* __restrict__ out)
{
  const int b = blockIdx.x;
  const int tid = threadIdx.x;
  const int lane = tid & 63;
  double* Pb = P0g + (size_t)b*NP1*WROW;
  const double* Qb = P1g + (size_t)b*NP1*WROW;
  const bool two = (nplanes > 1);

  __shared__ double pan[NP1][18];
  __shared__ double Ub[NB][256];
  __shared__ double xs[NP1];
  __shared__ double red[BD];
  __shared__ int perm[NP1];

  const float* chi = nullptr; const int* znum = nullptr;
  classify2(c0, c1, c2, chi, znum);
  const double rhsN = (double)syschg[b] * sqrt(90.0474);
  const float J0 = Jraw[0], J1 = Jraw[1], J2 = Jraw[2], J3 = Jraw[3];

  for (int i = tid; i < NP1; i += BD) perm[i] = i;
  __syncthreads();

  for (int p0 = 0; p0 < NP1; p0 += NB) {
    const int pw  = (NB < NP1 - p0) ? NB : (NP1 - p0);
    const int nr  = NP1 - p0;
    const int nrt = nr - pw;
    const int tc0 = p0 + pw;
    const int tc  = WROW - tc0;
    const bool first = (p0 == 0);
    // ---- panel load (first panel: fused plane-sum + diag; perm is identity then) ----
    for (int idx = tid; idx < nr*pw; idx += BD) {
      int r = (pw == NB) ? (idx >> 4) : (idx / pw);
      int c = (pw == NB) ? (idx & 15) : (idx - r*pw);
      double v;
      if (first) {
        size_t a = (size_t)r*WROW + c;
        v = Pb[a];
        if (two) v += Qb[a];
        if (r == c) {
          int z = znum[b*NATOM + r];
          float Jr = (z == 1) ? J0 : (z == 6) ? J1 : (z == 7) ? J2 : J3;
          v += (double)Jr*(double)Jr - DIAG_SUB;
        }
      } else {
        v = Pb[(size_t)perm[p0+r]*WROW + p0 + c];
      }
      pan[r][c] = v;
    }
    __syncthreads();
    // ---- factor panel: eager full-width updates, 2 barriers per column (r11-proven) ----
    for (int c = 0; c < pw; c++) {
      if (tid < 64) {
        double best = -1.0; int bi = c;
        for (int r = c + lane; r < nr; r += 64) {
          double av = fabs(pan[r][c]);
          if (av > best) { best = av; bi = r; }
        }
#pragma unroll
        for (int off = 32; off > 0; off >>= 1) {
          double ov = __shfl_down(best, off);
          int    oi = __shfl_down(bi, off);
          if (ov > best) { best = ov; bi = oi; }
        }
        int pr = __shfl(bi, 0);
        if (pr != c) {
          if (lane < pw) {
            double t = pan[c][lane]; pan[c][lane] = pan[pr][lane]; pan[pr][lane] = t;
          }
          if (lane == 0) {
            int t = perm[p0+c]; perm[p0+c] = perm[p0+pr]; perm[p0+pr] = t;
          }
        }
      }
      __syncthreads();
      const double dinv = 1.0 / pan[c][c];
      for (int r = c + 1 + tid; r < nr; r += BD) {
        double f = pan[r][c] * dinv;
        pan[r][c] = f;
        if (pw == NB) {
#pragma unroll
          for (int cc = c + 1; cc < NB; cc++) pan[r][cc] -= f * pan[c][cc];
        } else {
          for (int cc = c + 1; cc < pw; cc++) pan[r][cc] -= f * pan[c][cc];
        }
      }
      __syncthreads();
    }
    // ---- write back panel (L and U parts) via perm ----
    for (int idx = tid; idx < nr*pw; idx += BD) {
      int r = (pw == NB) ? (idx >> 4) : (idx / pw);
      int c = (pw == NB) ? (idx & 15) : (idx - r*pw);
      Pb[(size_t)perm[p0+r]*WROW + p0 + c] = pan[r][c];
    }
    __syncthreads();
    // ---- TRSM (thread-per-column) + trailing rank-16 update ----
    if (pw == NB) {
      if (tid < tc) {
        const int j = tc0 + tid;
        double v[NB];
#pragma unroll
        for (int c = 0; c < NB; c++) {
          const int pr = perm[p0+c];
          size_t a = (size_t)pr*WROW + j;
          double t = Pb[a];
          if (first) {
            if (two) t += Qb[a];
            if (pr == j && pr < NATOM) {          // diag keyed on PHYSICAL row
              int z = znum[b*NATOM + pr];
              float Jr = (z == 1) ? J0 : (z == 6) ? J1 : (z == 7) ? J2 : J3;
              t += (double)Jr*(double)Jr - DIAG_SUB;
            }
          }
          v[c] = t;
        }
#pragma unroll
        for (int c = 0; c < NB; c++)
#pragma unroll
          for (int r = c+1; r < NB; r++) v[r] -= pan[r][c]*v[c];
#pragma unroll
        for (int c = 0; c < NB; c++) {
          Pb[(size_t)perm[p0+c]*WROW + j] = v[c];
          Ub[c][tid] = v[c];
        }
      }
      __syncthreads();
      {
        const int jt = tid & 255;
        const int rgroup = tid >> 8;
        if (jt < tc) {
          double v[NB];
#pragma unroll
          for (int c = 0; c < NB; c++) v[c] = Ub[c][jt];
          for (int rr = rgroup; rr < nrt; rr += 4) {
            const int prr = perm[tc0 + rr];
            const size_t addr = (size_t)prr*WROW + tc0 + jt;
            double a = Pb[addr];
            if (first) {
              if (two) a += Qb[addr];
              if (prr == tc0 + jt && prr < NATOM) {  // diag keyed on PHYSICAL row
                int z = znum[b*NATOM + prr];
                float Jr = (z == 1) ? J0 : (z == 6) ? J1 : (z == 7) ? J2 : J3;
                a += (double)Jr*(double)Jr - DIAG_SUB;
              }
            }
#pragma unroll
            for (int m = 0; m < 8; m++) {
              double2 p2 = *(const double2*)&pan[NB+rr][2*m];
              a -= p2.x * v[2*m] + p2.y * v[2*m+1];
            }
            Pb[addr] = a;
          }
        }
      }
    } else {
      // last panel (pw < NB, no trailing rows; never the first panel)
      if (tid < tc) {
        const int j = tc0 + tid;
        double v[NB];
        for (int c = 0; c < pw; c++) v[c] = Pb[(size_t)perm[p0+c]*WROW + j];
        for (int c = 0; c < pw; c++)
          for (int r = c+1; r < pw; r++) v[r] -= pan[r][c]*v[c];
        for (int c = 0; c < pw; c++) Pb[(size_t)perm[p0+c]*WROW + j] = v[c];
      }
    }
    __syncthreads();
  }

  // ---- blocked backsolve (perm-indirected) ----
  for (int r = tid; r < NP1; r += BD) xs[r] = Pb[(size_t)perm[r]*WROW + 257];
  __syncthreads();
  for (int pb0 = 256; pb0 >= 0; pb0 -= NB) {
    const int w = (pb0 == 256) ? 1 : NB;
    if (tid < w*w) {
      int i = (w == NB) ? (tid >> 4) : 0;
      int c = (w == NB) ? (tid & 15) : 0;
      pan[i][c] = Pb[(size_t)perm[pb0+i]*WROW + pb0 + c];
    }
    __syncthreads();
    if (tid == 0) {
      for (int i = w-1; i >= 0; i--) {
        double s = xs[pb0+i];
        for (int c = i+1; c < w; c++) s -= pan[i][c]*xs[pb0+c];
        xs[pb0+i] = s / pan[i][i];
      }
    }
    __syncthreads();
    if (tid < pb0) {
      const double* rowp = &Pb[(size_t)perm[tid]*WROW + pb0];
      double s = 0.0;
      for (int c = 0; c < w; c++) s += rowp[c]*xs[pb0+c];
      xs[tid] -= s;
    }
    __syncthreads();
  }

  // ---- outputs: q + residual-identity energy ----
  for (int i = tid; i < NATOM; i += BD) out[b*NATOM + i] = (float)xs[i];
  const double lam = xs[NATOM];
  double contrib = 0.0;
  if (tid < NATOM) {
    double q  = xs[tid];
    double ch = (double)chi[b*NATOM + tid];
    int z = znum[b*NATOM + tid];
    float Jr = (z == 1) ? J0 : (z == 6) ? J1 : (z == 7) ? J2 : J3;
    contrib = q*ch + (double)Jr*(double)Jr*q*q;
  }
  __syncthreads();
  red[tid] = contrib;
  __syncthreads();
  for (int st = BD/2; st > 0; st >>= 1) {
    if (tid < st) red[tid] += red[tid + st];
    __syncthreads();
  }
  if (tid == 0)
    out[NBATCH*NATOM + b] = (float)(-0.5*(red[0] + lam*rhsN));
}

// ---------------- host launch ----------------
extern "C" void kernel_launch(void* const* d_in, const int* in_sizes, int n_in,
                              void* d_out, int out_size, void* d_ws, size_t ws_size,
                              hipStream_t stream)
{
  int iPos=-1, iCell=-1, iJ=-1, iQ=-1, cand[3]={-1,-1,-1}, nc=0;
  for (int i = 0; i < n_in; i++) {
    int s = in_sizes[i];
    if      (s == 6144) iPos  = i;
    else if (s == 72)   iCell = i;
    else if (s == 4)    iJ    = i;
    else if (s == 8)    iQ    = i;
    else if (s == 2048 && nc < 3) cand[nc++] = i;
  }
  if (!(iPos>=0 && iCell>=0 && iJ>=0 && iQ>=0 && nc>=2)) {
    iPos=iCell=iJ=iQ=-1; nc=0; cand[0]=cand[1]=cand[2]=-1;
    for (int i = 0; i < n_in; i++) {
      int s = in_sizes[i];
      if      (s == 24576) iPos  = i;
      else if (s == 288)   iCell = i;
      else if (s == 16)    iJ    = i;
      else if (s == 32)    iQ    = i;
      else if (s == 8192 && nc < 3) cand[nc++] = i;
    }
  }
  if (!(iPos>=0 && iCell>=0 && iJ>=0 && iQ>=0 && nc>=2)) {
    iPos=0; iCell=1; iJ=3; iQ=4; cand[0]=2; cand[1]=5; cand[2]=6; nc=3;
  }
  if (nc == 2) cand[2] = cand[1];

  const float* pos  = (const float*)d_in[iPos];
  const float* cell = (const float*)d_in[iCell];
  const float* Jraw = (const float*)d_in[iJ];
  const float* sysq = (const float*)d_in[iQ];
  const void*  c0   = d_in[cand[0]];
  const void*  c1   = d_in[cand[1]];
  const void*  c2   = d_in[cand[2]];
  float* out = (float*)d_out;

  // ws: [plane0][plane1][Tg][klist][kw][kcount]
  const size_t planeB = (size_t)NBATCH*NP1*WROW*sizeof(double);  // 4,243,584
  const size_t tgB = 2064384, klB = 327680, kwB = 163840;
  const size_t trigAll = tgB + klB + kwB + 64;
  int nplanes = (ws_size >= 2*planeB + trigAll) ? 2 : 1;

  char* ws = (char*)d_ws;
  double*  P0g = (double*)ws;
  double*  P1g = (nplanes > 1) ? (double*)(ws + planeB) : P0g;
  char* trigBase = ws + (size_t)nplanes*planeB;
  double2* Tg     = (double2*)trigBase;
  int4*    klist  = (int4*)  (trigBase + tgB);
  double*  kwa    = (double*)(trigBase + tgB + klB);
  int*     kcount = (int*)   (trigBase + tgB + klB + kwB);

  hipLaunchKernelGGL(prep,         dim3(NBATCH),      dim3(256), 0, stream,
                     pos, cell, Tg, klist, kwa, kcount, c0, c1, c2, sysq,
                     P0g, P1g, nplanes);
  hipLaunchKernelGGL(build_A_gemm, dim3(80*nplanes),  dim3(256), 0, stream,
                     Tg, klist, kwa, kcount, P0g, P1g, nplanes);
  hipLaunchKernelGGL(finish_A,     dim3(NBATCH),      dim3(256), 0, stream,
                     Tg, klist, kwa, kcount, P0g, P1g, nplanes);
  hipLaunchKernelGGL(solve_all,    dim3(NBATCH),      dim3(BD),  0, stream,
                     P0g, P1g, nplanes, c0, c1, c2, Jraw, sysq, out);
}